// Round 2
// baseline (24653.934 us; speedup 1.0000x reference)
//
#include <hip/hip_runtime.h>
#include <stdint.h>

typedef unsigned int u32;
typedef unsigned long long u64;
typedef unsigned short u16;
typedef __attribute__((ext_vector_type(8))) short s8;
typedef __attribute__((ext_vector_type(4))) float f4;

#define NWG 256
#define TPB 512
#define NB 64      // batch
#define TT 400     // seq len
#define EE 300     // embed dim
#define HEN 512    // encoder hidden
#define HD 1024    // decoder hidden
#define VV 50000   // vocab
#define DEC 80     // decode steps
#define NTL 3125   // VV/16 n-tiles
#define LCAP 512   // rescue list capacity
#define PBOFF 131072           // LDS: [0,128K) hA/enc-weights, [128K,+16K) combine/merge
#define SMEMSZ (PBOFF + 16384)
#define RESC 0.00837f          // 2^-8 * 1.002 * 2.09 safety (bf16 h + bf16 w + fp32 acc)

// barrier state word offsets inside p.bar
#define BAR_FULL_GRP  0       // 16 lines x 64 u32
#define BAR_DIR_GRP   1024    // 16 lines x 64 u32
#define BAR_FULL_ROOT 2048
#define BAR_FULL_EPO  2112
#define BAR_DIR_ROOT  2176    // + dir*64
#define BAR_DIR_EPO   2304    // + dir*64
#define BAR_WORDS     2560

struct P {
  const int* texts; const int* len; const float* emb;
  const float* ewih0; const float* ewhh0; const float* ebih0; const float* ebhh0;
  const float* ewih1; const float* ewhh1; const float* ebih1; const float* ebhh1;
  const float* dwih; const float* dwhh; const float* dbih; const float* dbhh;
  const float* outw; const float* outb;
  float* out;
  u16* owbf; float* xT; float* hTf; float* hTb; float* hTd; u16* hbf;
  u64* prt; int* tok; float* wn;
  u32* bar;
};

// Tree barrier: groups of 16 arrive on a private line; last of group hits root;
// last root sets epoch. HIP __syncthreads drains vmcnt before s_barrier, so all
// wg stores are in L2 before tid0's release fence flushes them.
__device__ __forceinline__ void gbarx(u32* grp, u32* root, u32* epo,
                                      u32 e, u32 gsz, u32 nroot) {
  __syncthreads();
  if (threadIdx.x == 0) {
    __builtin_amdgcn_fence(__ATOMIC_RELEASE, "agent");
    u32 old = __hip_atomic_fetch_add(grp, 1u, __ATOMIC_RELAXED, __HIP_MEMORY_SCOPE_AGENT);
    if (old == e * gsz + (gsz - 1u)) {
      u32 r = __hip_atomic_fetch_add(root, 1u, __ATOMIC_RELAXED, __HIP_MEMORY_SCOPE_AGENT);
      if (r == e * nroot + (nroot - 1u))
        __hip_atomic_store(epo, e + 1u, __ATOMIC_RELAXED, __HIP_MEMORY_SCOPE_AGENT);
    }
    while (__hip_atomic_load(epo, __ATOMIC_RELAXED, __HIP_MEMORY_SCOPE_AGENT) < e + 1u)
      __builtin_amdgcn_s_sleep(2);
    __builtin_amdgcn_fence(__ATOMIC_ACQUIRE, "agent");
  }
  __syncthreads();
}

__device__ __forceinline__ void gbarF(const P& p, u32& eb) {   // all 256 wgs
  gbarx(p.bar + BAR_FULL_GRP + ((blockIdx.x >> 4) << 6),
        p.bar + BAR_FULL_ROOT, p.bar + BAR_FULL_EPO, eb++, 16u, 16u);
}
__device__ __forceinline__ void gbarD(const P& p, u32& eb, int dir) { // 128 same-dir wgs
  gbarx(p.bar + BAR_DIR_GRP + ((blockIdx.x >> 4) << 6),
        p.bar + BAR_DIR_ROOT + dir * 64, p.bar + BAR_DIR_EPO + dir * 64,
        eb++, 16u, 8u);
}

__device__ __forceinline__ u32 fkey(float v) {
  u32 u = __float_as_uint(v);
  return (u & 0x80000000u) ? ~u : (u | 0x80000000u);
}
__device__ __forceinline__ u16 f2bf(float f) {   // RNE fp32->bf16
  u32 u = __float_as_uint(f);
  u32 r = u + 0x7FFFu + ((u >> 16) & 1u);
  return (u16)(r >> 16);
}
__device__ __forceinline__ float sigm(float x) { return 1.f / (1.f + expf(-x)); }

// ---- shared GRU epilogue: two-stage partial combine in 16KB LDS + activations
__device__ __forceinline__ void gru_combine_epi(
    char* smem, const f4& ar, const f4& az, const f4& ax, const f4& ah,
    int jjb, int HL, const float* bih, const float* bhh,
    const float* hc, float* ho, int mask_t, const int* lenp, u16* hbf_out)
{
  const int tid = threadIdx.x, lane = tid & 63, wv = tid >> 6;
  float* pb = (float*)(smem + PBOFF);     // [4][16][64]
  const int wl = wv & 3;
  if (wv < 4) {
    #pragma unroll
    for (int j = 0; j < 4; j++) {
      pb[((wl * 16 + j * 4 + 0) * 64) + lane] = ar[j];
      pb[((wl * 16 + j * 4 + 1) * 64) + lane] = az[j];
      pb[((wl * 16 + j * 4 + 2) * 64) + lane] = ax[j];
      pb[((wl * 16 + j * 4 + 3) * 64) + lane] = ah[j];
    }
  }
  __syncthreads();
  if (wv >= 4) {
    #pragma unroll
    for (int j = 0; j < 4; j++) {
      pb[((wl * 16 + j * 4 + 0) * 64) + lane] += ar[j];
      pb[((wl * 16 + j * 4 + 1) * 64) + lane] += az[j];
      pb[((wl * 16 + j * 4 + 2) * 64) + lane] += ax[j];
      pb[((wl * 16 + j * 4 + 3) * 64) + lane] += ah[j];
    }
  }
  __syncthreads();
  if (tid < 256) {
    int b = tid & 63, j = tid >> 6;
    int jj = jjb + j;
    float r = 0, z = 0, xn = 0, hn = 0;
    #pragma unroll
    for (int w = 0; w < 4; w++) {
      int base = ((w * 16 + j * 4) * 64) + b;
      r  += pb[base];
      z  += pb[base + 64];
      xn += pb[base + 128];
      hn += pb[base + 192];
    }
    r = sigm(r + bih[jj] + bhh[jj]);
    z = sigm(z + bih[HL + jj] + bhh[HL + jj]);
    float nn = tanhf(xn + bih[2 * HL + jj] + r * (hn + bhh[2 * HL + jj]));
    float hold = hc[(size_t)jj * NB + b];
    float hv = (1.f - z) * nn + z * hold;
    if (lenp && mask_t >= lenp[b]) hv = hold;
    ho[(size_t)jj * NB + b] = hv;
    if (hbf_out) hbf_out[(size_t)b * HD + jj] = f2bf(hv);
  }
}

// Encoder step: weights pre-staged in LDS [k][12] (gate-major within 48B row)
__device__ __forceinline__ void gru_enc(
    char* smem, int jjb, const float* xsrc,
    const float* bih, const float* bhh,
    const float* __restrict__ hc, float* ho, int tt, const int* lenp)
{
  const int tid = threadIdx.x, lane = tid & 63, wv = tid >> 6;
  const float* lw = (const float*)smem;
  const int KT = EE + HEN;
  const int vs = (wv * KT) >> 3, ve = ((wv + 1) * KT) >> 3;
  f4 ar = {0,0,0,0}, az = {0,0,0,0}, ax = {0,0,0,0}, ah = {0,0,0,0};
  int xe = ve < EE ? ve : EE;
  #pragma unroll 2
  for (int k = vs; k < xe; k++) {
    float xv = xsrc[(size_t)k * NB + lane];
    f4 w0 = *(const f4*)(lw + k * 12);
    f4 w1 = *(const f4*)(lw + k * 12 + 4);
    f4 w2 = *(const f4*)(lw + k * 12 + 8);
    ar += xv * w0; az += xv * w1; ax += xv * w2;
  }
  int hs = vs > EE ? vs : EE;
  #pragma unroll 2
  for (int k = hs; k < ve; k++) {
    float hv = hc[(size_t)(k - EE) * NB + lane];
    f4 w0 = *(const f4*)(lw + k * 12);
    f4 w1 = *(const f4*)(lw + k * 12 + 4);
    f4 w2 = *(const f4*)(lw + k * 12 + 8);
    ar += hv * w0; az += hv * w1; ah += hv * w2;
  }
  gru_combine_epi(smem, ar, az, ax, ah, jjb, HEN, bih, bhh, hc, ho, tt, lenp, nullptr);
}

// Decoder step: weights from global (80 steps only), x = emb[tok]
__device__ __forceinline__ void gru_dec(
    const P& p, char* smem, int jjb,
    const float* __restrict__ hc, float* ho)
{
  const int tid = threadIdx.x, lane = tid & 63, wv = tid >> 6;
  const float* wih = p.dwih; const float* whh = p.dwhh;
  const int KT = EE + HD;
  const int vs = (wv * KT) >> 3, ve = ((wv + 1) * KT) >> 3;
  f4 ar = {0,0,0,0}, az = {0,0,0,0}, ax = {0,0,0,0}, ah = {0,0,0,0};
  int xe = ve < EE ? ve : EE;
  if (vs < EE) {
    const float* xr = p.emb + (size_t)p.tok[lane] * EE;
    for (int k = vs; k < xe; k++) {
      float xv = xr[k];
      #pragma unroll
      for (int j = 0; j < 4; j++) {
        int jj = jjb + j;
        ar[j] = fmaf(xv, wih[(size_t)jj * EE + k], ar[j]);
        az[j] = fmaf(xv, wih[(size_t)(HD + jj) * EE + k], az[j]);
        ax[j] = fmaf(xv, wih[(size_t)(2 * HD + jj) * EE + k], ax[j]);
      }
    }
  }
  int hs = vs - EE; if (hs < 0) hs = 0;
  int he = ve - EE;
  for (int k = hs; k < he; k++) {
    float hv = hc[(size_t)k * NB + lane];
    #pragma unroll
    for (int j = 0; j < 4; j++) {
      int jj = jjb + j;
      ar[j] = fmaf(hv, whh[(size_t)jj * HD + k], ar[j]);
      az[j] = fmaf(hv, whh[(size_t)(HD + jj) * HD + k], az[j]);
      ah[j] = fmaf(hv, whh[(size_t)(2 * HD + jj) * HD + k], ah[j]);
    }
  }
  gru_combine_epi(smem, ar, az, ax, ah, jjb, HD, p.dbih, p.dbhh,
                  hc, ho, -1, nullptr, p.hbf);
}

__global__ void __launch_bounds__(TPB, 1) seq2seq_kernel(P p) {
  extern __shared__ __align__(16) char smem[];
  const int wg = blockIdx.x, tid = threadIdx.x;
  const int lane = tid & 63, wv = tid >> 6;
  const int gtid = wg * TPB + tid;
  u32 ebF = 0, ebD = 0;

  const int dir = wg >> 7;           // encoder: wgs 0..127 fwd, 128..255 bwd
  const int ejjb = (wg & 127) * 4;

  // ---------------- phase 0: one-time prep ----------------
  {
    // stage this wg's encoder weight slice into LDS: lw[k][g*4+j]
    const float* wih = dir ? p.ewih1 : p.ewih0;
    const float* whh = dir ? p.ewhh1 : p.ewhh0;
    float* lw = (float*)smem;
    for (int c = wv; c < 12; c += 8) {
      int g = c >> 2, j = c & 3;
      const float* sx = wih + (size_t)(g * HEN + ejjb + j) * EE;
      for (int k = lane; k < EE; k += 64) lw[k * 12 + c] = sx[k];
      const float* sh = whh + (size_t)(g * HEN + ejjb + j) * HEN;
      for (int k = lane; k < HEN; k += 64) lw[(EE + k) * 12 + c] = sh[k];
    }
    // out_w -> bf16 copy + per-row L2 norm (certified rescue bound)
    int gwv = wg * 8 + wv;
    for (int v = gwv; v < VV; v += 2048) {
      const float* wr = p.outw + (size_t)v * HD + lane * 16;
      u16* dst = p.owbf + (size_t)v * HD + lane * 16;
      float sa = 0.f;
      u32 pk[8];
      #pragma unroll
      for (int q = 0; q < 4; q++) {
        float4 f = *(const float4*)(wr + q * 4);
        sa += f.x * f.x + f.y * f.y + f.z * f.z + f.w * f.w;
        pk[q * 2 + 0] = (u32)f2bf(f.x) | ((u32)f2bf(f.y) << 16);
        pk[q * 2 + 1] = (u32)f2bf(f.z) | ((u32)f2bf(f.w) << 16);
      }
      *(uint4*)(dst)     = make_uint4(pk[0], pk[1], pk[2], pk[3]);
      *(uint4*)(dst + 8) = make_uint4(pk[4], pk[5], pk[6], pk[7]);
      #pragma unroll
      for (int d = 1; d < 64; d <<= 1) sa += __shfl_xor(sa, d);
      if (lane == 0) p.wn[v] = sqrtf(sa);
    }
    // gather+transpose encoder inputs: xT[t][k][b] = emb[texts[b][t]][k]
    const long long tot = (long long)TT * NB * EE;
    for (long long i = gtid; i < tot; i += (long long)NWG * TPB) {
      int t = (int)(i / (NB * EE));
      int rr = (int)(i % (NB * EE));
      int b2 = rr / EE, k = rr % EE;
      float v = p.emb[(size_t)p.texts[b2 * TT + t] * EE + k];
      p.xT[((size_t)t * EE + k) * NB + b2] = v;
    }
  }
  gbarF(p, ebF);

  // ---------------- phase 1: bidirectional encoder (per-direction barriers) --
  {
    const float* bih = dir ? p.ebih1 : p.ebih0;
    const float* bhh = dir ? p.ebhh1 : p.ebhh0;
    float* hbase = dir ? p.hTb : p.hTf;
    for (int t = 0; t < TT; t++) {
      int te = dir ? (TT - 1 - t) : t;
      const float* hc = hbase + (size_t)(t & 1) * HEN * NB;
      float* ho = hbase + (size_t)((t + 1) & 1) * HEN * NB;
      gru_enc(smem, ejjb, p.xT + (size_t)te * EE * NB, bih, bhh, hc, ho, te, p.len);
      gbarD(p, ebD, dir);
    }
  }
  gbarF(p, ebF);   // join fwd+bwd before reading both states

  // ---------------- phase 2: concat hidden, init tok ----------------
  {
    for (int i = gtid; i < HD * NB; i += NWG * TPB) {
      int k = i / NB, b2 = i % NB;
      float v = (k < HEN) ? p.hTf[(size_t)k * NB + b2] : p.hTb[(size_t)(k - HEN) * NB + b2];
      p.hTd[i] = v;
    }
    if (gtid < NB) p.tok[gtid] = 1;   // sos
  }
  gbarF(p, ebF);

  // ---------------- phase 3: decoder ----------------
  for (int s = 0; s < DEC; s++) {
    const float* hc = p.hTd + (size_t)(s & 1) * HD * NB;
    float* ho = p.hTd + (size_t)((s + 1) & 1) * HD * NB;
    // 3a: GRU step (emits bf16 row-major h)
    gru_dec(p, smem, wg * 4, hc, ho);
    gbarF(p, ebF);
    // 3b: bf16 MFMA logits + per-tile certified (lo,up) interval keys.
    // Full 64x1024 bf16 h staged once in 128KB LDS (XOR-swizzled 16B chunks:
    // chunk' = chunk ^ (row&7) -> conflict-free staging writes AND A-reads).
    // Then one barrier-free stream of 32 K-chunks: max MLP for the owbf scan.
    {
      u16* hA = (u16*)smem;                 // [64][128 chunks of 16B], swizzled
      float* hsq = (float*)(smem + PBOFF);  // [64]
      const int l15 = lane & 15, quad = lane >> 4;
      const int gw = wg * 8 + wv;
      const bool two = (gw + 2048) < NTL;
      if (tid < 64) hsq[tid] = 0.f;
      __syncthreads();
      for (int i = tid; i < 8192; i += TPB) {       // stage full hbf + ||h||^2
        int r = i >> 7, c = i & 127;
        uint4 q = *(const uint4*)(p.hbf + (size_t)r * HD + c * 8);
        *(uint4*)(hA + (size_t)r * 1024 + ((c ^ (r & 7)) * 8)) = q;
        u32 uu[4] = {q.x, q.y, q.z, q.w};
        float sq = 0.f;
        #pragma unroll
        for (int t2 = 0; t2 < 4; t2++) {
          float lo = __uint_as_float(uu[t2] << 16);
          float hi = __uint_as_float(uu[t2] & 0xffff0000u);
          sq = fmaf(lo, lo, fmaf(hi, hi, sq));
        }
        atomicAdd(&hsq[r], sq);
      }
      __syncthreads();
      f4 acc0[4], acc1[4];
      #pragma unroll
      for (int m = 0; m < 4; m++) {
        #pragma unroll
        for (int r = 0; r < 4; r++) { acc0[m][r] = 0.f; acc1[m][r] = 0.f; }
      }
      const u16* bp0 = p.owbf + (size_t)(gw * 16 + l15) * HD + quad * 8;
      const u16* bp1 = bp0 + (size_t)2048 * 16 * HD;
      const int x7 = l15 & 7;
      const u16* hrow = hA + l15 * 1024;
      #pragma unroll 4
      for (int kc = 0; kc < 32; kc++) {
        int ci = ((kc * 4 + quad) ^ x7) * 8;
        s8 b0 = *(const s8*)(bp0 + kc * 32);
        s8 a0 = *(const s8*)(hrow + ci);
        s8 a1 = *(const s8*)(hrow + 16384 + ci);
        s8 a2 = *(const s8*)(hrow + 32768 + ci);
        s8 a3 = *(const s8*)(hrow + 49152 + ci);
        acc0[0] = __builtin_amdgcn_mfma_f32_16x16x32_bf16(a0, b0, acc0[0], 0, 0, 0);
        acc0[1] = __builtin_amdgcn_mfma_f32_16x16x32_bf16(a1, b0, acc0[1], 0, 0, 0);
        acc0[2] = __builtin_amdgcn_mfma_f32_16x16x32_bf16(a2, b0, acc0[2], 0, 0, 0);
        acc0[3] = __builtin_amdgcn_mfma_f32_16x16x32_bf16(a3, b0, acc0[3], 0, 0, 0);
        if (two) {
          s8 b1 = *(const s8*)(bp1 + kc * 32);
          acc1[0] = __builtin_amdgcn_mfma_f32_16x16x32_bf16(a0, b1, acc1[0], 0, 0, 0);
          acc1[1] = __builtin_amdgcn_mfma_f32_16x16x32_bf16(a1, b1, acc1[1], 0, 0, 0);
          acc1[2] = __builtin_amdgcn_mfma_f32_16x16x32_bf16(a2, b1, acc1[2], 0, 0, 0);
          acc1[3] = __builtin_amdgcn_mfma_f32_16x16x32_bf16(a3, b1, acc1[3], 0, 0, 0);
        }
      }
      float hroot[4][4];
      #pragma unroll
      for (int m = 0; m < 4; m++)
        #pragma unroll
        for (int r = 0; r < 4; r++)
          hroot[m][r] = sqrtf(hsq[m * 16 + quad * 4 + r]);
      auto epi = [&](int nt, f4* acc) {
        int col = nt * 16 + l15;
        float bias = p.outb[col];
        float wnc = p.wn[col];
        #pragma unroll
        for (int m = 0; m < 4; m++) {
          #pragma unroll
          for (int r = 0; r < 4; r++) {
            float v = acc[m][r] + bias;
            float e = RESC * hroot[m][r] * wnc + 1e-5f;
            u32 klo = fkey(v - e), kup = fkey(v + e);
            #pragma unroll
            for (int d = 1; d < 16; d <<= 1) {
              u32 ol = __shfl_xor(klo, d); if (ol > klo) klo = ol;
              u32 ou = __shfl_xor(kup, d); if (ou > kup) kup = ou;
            }
            if (l15 == 0)
              p.prt[(size_t)nt * 64 + (m * 16 + quad * 4 + r)] =
                  ((u64)klo << 32) | kup;
          }
        }
      };
      epi(gw, acc0);
      if (two) epi(gw + 2048, acc1);
    }
    gbarF(p, ebF);
    // 3c: threshold T = max lo; rescue every tile with up >= T in exact fp32
    if (wg < NB) {
      const int b = wg;
      char* ms = smem + PBOFF;
      float* hb = (float*)ms;                   // [1024] exact fp32 h
      u64* red = (u64*)(ms + 4096);             // [8]
      u64* gmp = (u64*)(ms + 4160);
      u64* bestp = (u64*)(ms + 4168);
      int* ncp = (int*)(ms + 4176);
      int* list = (int*)(ms + 4192);            // [LCAP]
      for (int i = tid; i < HD; i += TPB) hb[i] = ho[(size_t)i * NB + b];
      if (tid == 0) { *bestp = 0ull; *ncp = 0; }
      __syncthreads();
      u64 mx = 0;
      for (int nt = tid; nt < NTL; nt += TPB) {
        u64 v = p.prt[(size_t)nt * 64 + b];
        if (v > mx) mx = v;
      }
      #pragma unroll
      for (int d = 1; d < 64; d <<= 1) { u64 o = __shfl_xor(mx, d); if (o > mx) mx = o; }
      if (lane == 0) red[wv] = mx;
      __syncthreads();
      if (tid == 0) {
        u64 g = red[0];
        for (int w2 = 1; w2 < 8; w2++) if (red[w2] > g) g = red[w2];
        *gmp = g;
      }
      __syncthreads();
      const u32 thr = (u32)(*gmp >> 32);        // fkey(T), T = max of lo
      for (int nt = tid; nt < NTL; nt += TPB) {
        if ((u32)p.prt[(size_t)nt * 64 + b] >= thr) {   // up >= T
          int ix = atomicAdd(ncp, 1);
          if (ix < LCAP) list[ix] = nt;
        }
      }
      __syncthreads();
      int total = *ncp;
      int nc = total < LCAP ? total : LCAP;
      const int c16 = tid >> 5, seg = tid & 31;
      u64 lb = 0;
      auto rescue = [&](int nt) {
        int v = nt * 16 + c16;
        const float* wr = p.outw + (size_t)v * HD;
        float sm = 0.f;
        #pragma unroll 8
        for (int i = 0; i < 32; i++) {
          int k = seg + 32 * i;
          sm = fmaf(hb[k], wr[k], sm);
        }
        #pragma unroll
        for (int d = 1; d < 32; d <<= 1) sm += __shfl_xor(sm, d);
        if (seg == 0) {
          float lg = sm + p.outb[v];
          u64 k2 = ((u64)fkey(lg) << 32) | (~(u32)v);   // ~v: lowest idx wins ties
          if (k2 > lb) lb = k2;
        }
      };
      for (int ci = 0; ci < nc; ci++) rescue(list[ci]);
      if (total > LCAP) {                       // certified fallback
        for (int nt = 0; nt < NTL; nt++)
          if ((u32)p.prt[(size_t)nt * 64 + b] >= thr) rescue(nt);
      }
      if (seg == 0 && lb) atomicMax((unsigned long long*)bestp, lb);
      __syncthreads();
      if (tid == 0) {
        u32 v = ~(u32)(*bestp);
        p.tok[b] = (int)v;
        p.out[b * DEC + s] = (float)v;
      }
    }
    gbarF(p, ebF);
  }
}

__global__ void seq2seq_init(u32* bar, float* hTf, float* hTb) {
  int g = blockIdx.x * blockDim.x + threadIdx.x;
  if (g < BAR_WORDS) bar[g] = 0u;
  int n = 2 * HEN * NB;
  for (int i = g; i < n; i += gridDim.x * blockDim.x) { hTf[i] = 0.f; hTb[i] = 0.f; }
}

extern "C" void kernel_launch(void* const* d_in, const int* in_sizes, int n_in,
                              void* d_out, int out_size, void* d_ws, size_t ws_size,
                              hipStream_t stream) {
  char* w = (char*)d_ws;
  size_t off = 0;
  auto carve = [&](size_t n) {
    void* q = w + off;
    off = (off + n + 255) & ~(size_t)255;
    return q;
  };
  P p;
  p.texts = (const int*)d_in[0];
  p.len   = (const int*)d_in[1];
  p.emb   = (const float*)d_in[2];
  p.ewih0 = (const float*)d_in[3];  p.ewhh0 = (const float*)d_in[4];
  p.ebih0 = (const float*)d_in[5];  p.ebhh0 = (const float*)d_in[6];
  p.ewih1 = (const float*)d_in[7];  p.ewhh1 = (const float*)d_in[8];
  p.ebih1 = (const float*)d_in[9];  p.ebhh1 = (const float*)d_in[10];
  p.dwih  = (const float*)d_in[11]; p.dwhh  = (const float*)d_in[12];
  p.dbih  = (const float*)d_in[13]; p.dbhh  = (const float*)d_in[14];
  p.outw  = (const float*)d_in[15]; p.outb  = (const float*)d_in[16];
  p.out   = (float*)d_out;
  p.owbf  = (u16*)carve((size_t)VV * HD * 2);
  p.xT    = (float*)carve((size_t)TT * EE * NB * 4);
  p.hTf   = (float*)carve((size_t)2 * HEN * NB * 4);
  p.hTb   = (float*)carve((size_t)2 * HEN * NB * 4);
  p.hTd   = (float*)carve((size_t)2 * HD * NB * 4);
  p.hbf   = (u16*)carve((size_t)NB * HD * 2);
  p.prt   = (u64*)carve((size_t)NTL * 64 * 8);
  p.tok   = (int*)carve(256);
  p.wn    = (float*)carve((size_t)VV * 4);
  p.bar   = (u32*)carve(BAR_WORDS * 4);
  if (off > ws_size) return;  // workspace too small: fail visibly

  hipFuncSetAttribute((const void*)seq2seq_kernel,
                      hipFuncAttributeMaxDynamicSharedMemorySize, SMEMSZ);

  hipLaunchKernelGGL(seq2seq_init, dim3(64), dim3(256), 0, stream,
                     p.bar, p.hTf, p.hTb);
  void* args[] = { &p };
  hipError_t e = hipLaunchCooperativeKernel((void*)seq2seq_kernel,
                                            dim3(NWG), dim3(TPB), args, SMEMSZ, stream);
  if (e != hipSuccess) {
    seq2seq_kernel<<<dim3(NWG), dim3(TPB), SMEMSZ, stream>>>(p);
  }
}

// Round 3
// 21425.934 us; speedup vs baseline: 1.1507x; 1.1507x over previous
//
#include <hip/hip_runtime.h>
#include <stdint.h>

typedef unsigned int u32;
typedef unsigned long long u64;
typedef unsigned short u16;
typedef __attribute__((ext_vector_type(8))) short s8;
typedef __attribute__((ext_vector_type(4))) float f4;

#define NWG 256
#define TPB 512
#define NB 64      // batch
#define TT 400     // seq len
#define EE 300     // embed dim
#define HEN 512    // encoder hidden
#define HD 1024    // decoder hidden
#define VV 50000   // vocab
#define DEC 80     // decode steps
#define NTL 3125   // VV/16 n-tiles
#define LCAP 512   // rescue list capacity
#define PBOFF 131072           // LDS: [0,128K) hA/enc-weights, [128K,+16K) combine/merge
#define SMEMSZ (PBOFF + 16384)
#define RESC 0.00837f          // 2^-8 * 1.002 * 2.09 safety (bf16 h + bf16 w + fp32 acc)

// barrier state word offsets inside p.bar
#define BAR_FULL_GRP  0       // 16 lines x 64 u32
#define BAR_DIR_GRP   1024    // 16 lines x 64 u32
#define BAR_FULL_ROOT 2048
#define BAR_FULL_EPO  2112
#define BAR_DIR_ROOT  2176    // + dir*64
#define BAR_DIR_EPO   2304    // + dir*64
#define BAR_WORDS     2560

struct P {
  const int* texts; const int* len; const float* emb;
  const float* ewih0; const float* ewhh0; const float* ebih0; const float* ebhh0;
  const float* ewih1; const float* ewhh1; const float* ebih1; const float* ebhh1;
  const float* dwih; const float* dwhh; const float* dbih; const float* dbhh;
  const float* outw; const float* outb;
  float* out;
  u16* owbf; float* xT; float* hTf; float* hTb; float* hTd; u16* hbf;
  u64* prt; int* tok; float* wn;
  u32* bar;
};

// ---- coherent (agent-scope, cache-bypassing) accessors for MUTABLE cross-wg
// data. These emit sc0/sc1 loads/stores that hit the coherence point directly,
// so NO cache-wide fences are needed and read-only data stays L2-resident.
__device__ __forceinline__ float cld(const float* a) {
  return __hip_atomic_load(const_cast<float*>(a), __ATOMIC_RELAXED, __HIP_MEMORY_SCOPE_AGENT);
}
__device__ __forceinline__ void cst(float* a, float v) {
  __hip_atomic_store(a, v, __ATOMIC_RELAXED, __HIP_MEMORY_SCOPE_AGENT);
}
__device__ __forceinline__ u64 cld(const u64* a) {
  return __hip_atomic_load(const_cast<u64*>(a), __ATOMIC_RELAXED, __HIP_MEMORY_SCOPE_AGENT);
}
__device__ __forceinline__ void cst(u64* a, u64 v) {
  __hip_atomic_store(a, v, __ATOMIC_RELAXED, __HIP_MEMORY_SCOPE_AGENT);
}
__device__ __forceinline__ int cld(const int* a) {
  return __hip_atomic_load(const_cast<int*>(a), __ATOMIC_RELAXED, __HIP_MEMORY_SCOPE_AGENT);
}
__device__ __forceinline__ void cst(int* a, int v) {
  __hip_atomic_store(a, v, __ATOMIC_RELAXED, __HIP_MEMORY_SCOPE_AGENT);
}
__device__ __forceinline__ void cst(u16* a, u16 v) {
  __hip_atomic_store(a, v, __ATOMIC_RELAXED, __HIP_MEMORY_SCOPE_AGENT);
}

// Tree barrier: groups of 16 arrive on a private line; last of group hits root;
// last root sets epoch. __syncthreads drains vmcnt, so all of this wg's
// coherent stores are at the coherence point before tid0 arrives.
// FEN=true additionally does agent release/acquire fences (L2 wb/inv) — used
// exactly ONCE, after phase 0, to publish the plain-stored read-only data.
template<bool FEN>
__device__ __forceinline__ void gbarx(u32* grp, u32* root, u32* epo,
                                      u32 e, u32 gsz, u32 nroot) {
  __syncthreads();
  if (threadIdx.x == 0) {
    if (FEN) __builtin_amdgcn_fence(__ATOMIC_RELEASE, "agent");
    u32 old = __hip_atomic_fetch_add(grp, 1u, __ATOMIC_RELAXED, __HIP_MEMORY_SCOPE_AGENT);
    if (old == e * gsz + (gsz - 1u)) {
      u32 r = __hip_atomic_fetch_add(root, 1u, __ATOMIC_RELAXED, __HIP_MEMORY_SCOPE_AGENT);
      if (r == e * nroot + (nroot - 1u))
        __hip_atomic_store(epo, e + 1u, __ATOMIC_RELAXED, __HIP_MEMORY_SCOPE_AGENT);
    }
    while (__hip_atomic_load(epo, __ATOMIC_RELAXED, __HIP_MEMORY_SCOPE_AGENT) < e + 1u)
      __builtin_amdgcn_s_sleep(16);
    if (FEN) __builtin_amdgcn_fence(__ATOMIC_ACQUIRE, "agent");
  }
  __syncthreads();
}

template<bool FEN>
__device__ __forceinline__ void gbarF(const P& p, u32& eb) {   // all 256 wgs
  gbarx<FEN>(p.bar + BAR_FULL_GRP + ((blockIdx.x >> 4) << 6),
             p.bar + BAR_FULL_ROOT, p.bar + BAR_FULL_EPO, eb++, 16u, 16u);
}
__device__ __forceinline__ void gbarD(const P& p, u32& eb, int dir) { // 128 same-dir wgs
  gbarx<false>(p.bar + BAR_DIR_GRP + ((blockIdx.x >> 4) << 6),
               p.bar + BAR_DIR_ROOT + dir * 64, p.bar + BAR_DIR_EPO + dir * 64,
               eb++, 16u, 8u);
}

__device__ __forceinline__ u32 fkey(float v) {
  u32 u = __float_as_uint(v);
  return (u & 0x80000000u) ? ~u : (u | 0x80000000u);
}
__device__ __forceinline__ u16 f2bf(float f) {   // RNE fp32->bf16
  u32 u = __float_as_uint(f);
  u32 r = u + 0x7FFFu + ((u >> 16) & 1u);
  return (u16)(r >> 16);
}
__device__ __forceinline__ float sigm(float x) { return 1.f / (1.f + expf(-x)); }

// ---- shared GRU epilogue: two-stage partial combine in 16KB LDS + activations
// hc reads / ho writes are COHERENT (cross-wg mutable state).
__device__ __forceinline__ void gru_combine_epi(
    char* smem, const f4& ar, const f4& az, const f4& ax, const f4& ah,
    int jjb, int HL, const float* bih, const float* bhh,
    const float* hc, float* ho, int mask_t, const int* lenp, u16* hbf_out)
{
  const int tid = threadIdx.x, lane = tid & 63, wv = tid >> 6;
  float* pb = (float*)(smem + PBOFF);     // [4][16][64]
  const int wl = wv & 3;
  if (wv < 4) {
    #pragma unroll
    for (int j = 0; j < 4; j++) {
      pb[((wl * 16 + j * 4 + 0) * 64) + lane] = ar[j];
      pb[((wl * 16 + j * 4 + 1) * 64) + lane] = az[j];
      pb[((wl * 16 + j * 4 + 2) * 64) + lane] = ax[j];
      pb[((wl * 16 + j * 4 + 3) * 64) + lane] = ah[j];
    }
  }
  __syncthreads();
  if (wv >= 4) {
    #pragma unroll
    for (int j = 0; j < 4; j++) {
      pb[((wl * 16 + j * 4 + 0) * 64) + lane] += ar[j];
      pb[((wl * 16 + j * 4 + 1) * 64) + lane] += az[j];
      pb[((wl * 16 + j * 4 + 2) * 64) + lane] += ax[j];
      pb[((wl * 16 + j * 4 + 3) * 64) + lane] += ah[j];
    }
  }
  __syncthreads();
  if (tid < 256) {
    int b = tid & 63, j = tid >> 6;
    int jj = jjb + j;
    float r = 0, z = 0, xn = 0, hn = 0;
    #pragma unroll
    for (int w = 0; w < 4; w++) {
      int base = ((w * 16 + j * 4) * 64) + b;
      r  += pb[base];
      z  += pb[base + 64];
      xn += pb[base + 128];
      hn += pb[base + 192];
    }
    r = sigm(r + bih[jj] + bhh[jj]);
    z = sigm(z + bih[HL + jj] + bhh[HL + jj]);
    float nn = tanhf(xn + bih[2 * HL + jj] + r * (hn + bhh[2 * HL + jj]));
    float hold = cld(hc + (size_t)jj * NB + b);
    float hv = (1.f - z) * nn + z * hold;
    if (lenp && mask_t >= lenp[b]) hv = hold;
    cst(ho + (size_t)jj * NB + b, hv);
    if (hbf_out) cst(hbf_out + (size_t)b * HD + jj, f2bf(hv));
  }
}

// Encoder step: weights pre-staged in LDS [k][12] (gate-major within 48B row)
__device__ __forceinline__ void gru_enc(
    char* smem, int jjb, const float* xsrc,
    const float* bih, const float* bhh,
    const float* __restrict__ hc, float* ho, int tt, const int* lenp)
{
  const int tid = threadIdx.x, lane = tid & 63, wv = tid >> 6;
  const float* lw = (const float*)smem;
  const int KT = EE + HEN;
  const int vs = (wv * KT) >> 3, ve = ((wv + 1) * KT) >> 3;
  f4 ar = {0,0,0,0}, az = {0,0,0,0}, ax = {0,0,0,0}, ah = {0,0,0,0};
  int xe = ve < EE ? ve : EE;
  #pragma unroll 2
  for (int k = vs; k < xe; k++) {
    float xv = xsrc[(size_t)k * NB + lane];        // read-only, cached
    f4 w0 = *(const f4*)(lw + k * 12);
    f4 w1 = *(const f4*)(lw + k * 12 + 4);
    f4 w2 = *(const f4*)(lw + k * 12 + 8);
    ar += xv * w0; az += xv * w1; ax += xv * w2;
  }
  int hs = vs > EE ? vs : EE;
  #pragma unroll 2
  for (int k = hs; k < ve; k++) {
    float hv = cld(hc + (size_t)(k - EE) * NB + lane);   // mutable, coherent
    f4 w0 = *(const f4*)(lw + k * 12);
    f4 w1 = *(const f4*)(lw + k * 12 + 4);
    f4 w2 = *(const f4*)(lw + k * 12 + 8);
    ar += hv * w0; az += hv * w1; ah += hv * w2;
  }
  gru_combine_epi(smem, ar, az, ax, ah, jjb, HEN, bih, bhh, hc, ho, tt, lenp, nullptr);
}

// Decoder step: weights from global (cached, stay L2-resident), x = emb[tok]
__device__ __forceinline__ void gru_dec(
    const P& p, char* smem, int jjb,
    const float* __restrict__ hc, float* ho)
{
  const int tid = threadIdx.x, lane = tid & 63, wv = tid >> 6;
  const float* wih = p.dwih; const float* whh = p.dwhh;
  const int KT = EE + HD;
  const int vs = (wv * KT) >> 3, ve = ((wv + 1) * KT) >> 3;
  f4 ar = {0,0,0,0}, az = {0,0,0,0}, ax = {0,0,0,0}, ah = {0,0,0,0};
  int xe = ve < EE ? ve : EE;
  if (vs < EE) {
    const float* xr = p.emb + (size_t)cld(p.tok + lane) * EE;
    for (int k = vs; k < xe; k++) {
      float xv = xr[k];
      #pragma unroll
      for (int j = 0; j < 4; j++) {
        int jj = jjb + j;
        ar[j] = fmaf(xv, wih[(size_t)jj * EE + k], ar[j]);
        az[j] = fmaf(xv, wih[(size_t)(HD + jj) * EE + k], az[j]);
        ax[j] = fmaf(xv, wih[(size_t)(2 * HD + jj) * EE + k], ax[j]);
      }
    }
  }
  int hs = vs - EE; if (hs < 0) hs = 0;
  int he = ve - EE;
  for (int k = hs; k < he; k++) {
    float hv = cld(hc + (size_t)k * NB + lane);
    #pragma unroll
    for (int j = 0; j < 4; j++) {
      int jj = jjb + j;
      ar[j] = fmaf(hv, whh[(size_t)jj * HD + k], ar[j]);
      az[j] = fmaf(hv, whh[(size_t)(HD + jj) * HD + k], az[j]);
      ah[j] = fmaf(hv, whh[(size_t)(2 * HD + jj) * HD + k], ah[j]);
    }
  }
  gru_combine_epi(smem, ar, az, ax, ah, jjb, HD, p.dbih, p.dbhh,
                  hc, ho, -1, nullptr, p.hbf);
}

__global__ void __launch_bounds__(TPB, 1) seq2seq_kernel(P p) {
  extern __shared__ __align__(16) char smem[];
  const int wg = blockIdx.x, tid = threadIdx.x;
  const int lane = tid & 63, wv = tid >> 6;
  const int gtid = wg * TPB + tid;
  u32 ebF = 0, ebD = 0;

  const int dir = wg >> 7;           // encoder: wgs 0..127 fwd, 128..255 bwd
  const int ejjb = (wg & 127) * 4;

  // ---------------- phase 0: one-time prep ----------------
  {
    // stage this wg's encoder weight slice into LDS: lw[k][g*4+j]
    const float* wih = dir ? p.ewih1 : p.ewih0;
    const float* whh = dir ? p.ewhh1 : p.ewhh0;
    float* lw = (float*)smem;
    for (int c = wv; c < 12; c += 8) {
      int g = c >> 2, j = c & 3;
      const float* sx = wih + (size_t)(g * HEN + ejjb + j) * EE;
      for (int k = lane; k < EE; k += 64) lw[k * 12 + c] = sx[k];
      const float* sh = whh + (size_t)(g * HEN + ejjb + j) * HEN;
      for (int k = lane; k < HEN; k += 64) lw[(EE + k) * 12 + c] = sh[k];
    }
    // out_w -> bf16 copy + per-row L2 norm (certified rescue bound)
    int gwv = wg * 8 + wv;
    for (int v = gwv; v < VV; v += 2048) {
      const float* wr = p.outw + (size_t)v * HD + lane * 16;
      u16* dst = p.owbf + (size_t)v * HD + lane * 16;
      float sa = 0.f;
      u32 pk[8];
      #pragma unroll
      for (int q = 0; q < 4; q++) {
        float4 f = *(const float4*)(wr + q * 4);
        sa += f.x * f.x + f.y * f.y + f.z * f.z + f.w * f.w;
        pk[q * 2 + 0] = (u32)f2bf(f.x) | ((u32)f2bf(f.y) << 16);
        pk[q * 2 + 1] = (u32)f2bf(f.z) | ((u32)f2bf(f.w) << 16);
      }
      *(uint4*)(dst)     = make_uint4(pk[0], pk[1], pk[2], pk[3]);
      *(uint4*)(dst + 8) = make_uint4(pk[4], pk[5], pk[6], pk[7]);
      #pragma unroll
      for (int d = 1; d < 64; d <<= 1) sa += __shfl_xor(sa, d);
      if (lane == 0) p.wn[v] = sqrtf(sa);
    }
    // gather+transpose encoder inputs: xT[t][k][b] = emb[texts[b][t]][k]
    const long long tot = (long long)TT * NB * EE;
    for (long long i = gtid; i < tot; i += (long long)NWG * TPB) {
      int t = (int)(i / (NB * EE));
      int rr = (int)(i % (NB * EE));
      int b2 = rr / EE, k = rr % EE;
      float v = p.emb[(size_t)p.texts[b2 * TT + t] * EE + k];
      p.xT[((size_t)t * EE + k) * NB + b2] = v;
    }
  }
  gbarF<true>(p, ebF);   // the ONLY fenced barrier: publishes owbf/xT/wn

  // ---------------- phase 1: bidirectional encoder (per-direction barriers) --
  {
    const float* bih = dir ? p.ebih1 : p.ebih0;
    const float* bhh = dir ? p.ebhh1 : p.ebhh0;
    float* hbase = dir ? p.hTb : p.hTf;
    for (int t = 0; t < TT; t++) {
      int te = dir ? (TT - 1 - t) : t;
      const float* hc = hbase + (size_t)(t & 1) * HEN * NB;
      float* ho = hbase + (size_t)((t + 1) & 1) * HEN * NB;
      gru_enc(smem, ejjb, p.xT + (size_t)te * EE * NB, bih, bhh, hc, ho, te, p.len);
      gbarD(p, ebD, dir);
    }
  }
  gbarF<false>(p, ebF);   // join fwd+bwd before reading both states

  // ---------------- phase 2: concat hidden, init tok ----------------
  {
    for (int i = gtid; i < HD * NB; i += NWG * TPB) {
      int k = i / NB, b2 = i % NB;
      float v = (k < HEN) ? cld(p.hTf + (size_t)k * NB + b2)
                          : cld(p.hTb + (size_t)(k - HEN) * NB + b2);
      cst(p.hTd + i, v);
    }
    if (gtid < NB) cst(p.tok + gtid, 1);   // sos
  }
  gbarF<false>(p, ebF);

  // ---------------- phase 3: decoder ----------------
  for (int s = 0; s < DEC; s++) {
    const float* hc = p.hTd + (size_t)(s & 1) * HD * NB;
    float* ho = p.hTd + (size_t)((s + 1) & 1) * HD * NB;
    // 3a: GRU step (emits bf16 row-major h)
    gru_dec(p, smem, wg * 4, hc, ho);
    gbarF<false>(p, ebF);
    // 3b: bf16 MFMA logits + per-tile certified (lo,up) interval keys.
    // Full 64x1024 bf16 h staged once in 128KB LDS (XOR-swizzled 16B chunks).
    {
      u16* hA = (u16*)smem;                 // [64][128 chunks of 16B], swizzled
      float* hsq = (float*)(smem + PBOFF);  // [64]
      const int l15 = lane & 15, quad = lane >> 4;
      const int gw = wg * 8 + wv;
      const bool two = (gw + 2048) < NTL;
      if (tid < 64) hsq[tid] = 0.f;
      __syncthreads();
      const u64* hb64 = (const u64*)p.hbf;        // 256 u64 per row
      u64* hA64 = (u64*)hA;
      for (int i = tid; i < 16384; i += TPB) {    // stage full hbf + ||h||^2
        int r = i >> 8, c = i & 255;
        u64 q = cld(hb64 + (size_t)r * 256 + c);  // coherent (mutable)
        int cc = c >> 1;                          // 16B chunk index
        hA64[(size_t)r * 256 + ((cc ^ (r & 7)) * 2) + (c & 1)] = q;
        u32 uu[2] = {(u32)q, (u32)(q >> 32)};
        float sq = 0.f;
        #pragma unroll
        for (int t2 = 0; t2 < 2; t2++) {
          float lo = __uint_as_float(uu[t2] << 16);
          float hi = __uint_as_float(uu[t2] & 0xffff0000u);
          sq = fmaf(lo, lo, fmaf(hi, hi, sq));
        }
        atomicAdd(&hsq[r], sq);
      }
      __syncthreads();
      f4 acc0[4], acc1[4];
      #pragma unroll
      for (int m = 0; m < 4; m++) {
        #pragma unroll
        for (int r = 0; r < 4; r++) { acc0[m][r] = 0.f; acc1[m][r] = 0.f; }
      }
      const u16* bp0 = p.owbf + (size_t)(gw * 16 + l15) * HD + quad * 8;  // cached
      const u16* bp1 = bp0 + (size_t)2048 * 16 * HD;
      const int x7 = l15 & 7;
      const u16* hrow = hA + l15 * 1024;
      #pragma unroll 4
      for (int kc = 0; kc < 32; kc++) {
        int ci = ((kc * 4 + quad) ^ x7) * 8;
        s8 b0 = *(const s8*)(bp0 + kc * 32);
        s8 a0 = *(const s8*)(hrow + ci);
        s8 a1 = *(const s8*)(hrow + 16384 + ci);
        s8 a2 = *(const s8*)(hrow + 32768 + ci);
        s8 a3 = *(const s8*)(hrow + 49152 + ci);
        acc0[0] = __builtin_amdgcn_mfma_f32_16x16x32_bf16(a0, b0, acc0[0], 0, 0, 0);
        acc0[1] = __builtin_amdgcn_mfma_f32_16x16x32_bf16(a1, b0, acc0[1], 0, 0, 0);
        acc0[2] = __builtin_amdgcn_mfma_f32_16x16x32_bf16(a2, b0, acc0[2], 0, 0, 0);
        acc0[3] = __builtin_amdgcn_mfma_f32_16x16x32_bf16(a3, b0, acc0[3], 0, 0, 0);
        if (two) {
          s8 b1 = *(const s8*)(bp1 + kc * 32);
          acc1[0] = __builtin_amdgcn_mfma_f32_16x16x32_bf16(a0, b1, acc1[0], 0, 0, 0);
          acc1[1] = __builtin_amdgcn_mfma_f32_16x16x32_bf16(a1, b1, acc1[1], 0, 0, 0);
          acc1[2] = __builtin_amdgcn_mfma_f32_16x16x32_bf16(a2, b1, acc1[2], 0, 0, 0);
          acc1[3] = __builtin_amdgcn_mfma_f32_16x16x32_bf16(a3, b1, acc1[3], 0, 0, 0);
        }
      }
      float hroot[4][4];
      #pragma unroll
      for (int m = 0; m < 4; m++)
        #pragma unroll
        for (int r = 0; r < 4; r++)
          hroot[m][r] = sqrtf(hsq[m * 16 + quad * 4 + r]);
      auto epi = [&](int nt, f4* acc) {
        int col = nt * 16 + l15;
        float bias = p.outb[col];
        float wnc = p.wn[col];
        #pragma unroll
        for (int m = 0; m < 4; m++) {
          #pragma unroll
          for (int r = 0; r < 4; r++) {
            float v = acc[m][r] + bias;
            float e = RESC * hroot[m][r] * wnc + 1e-5f;
            u32 klo = fkey(v - e), kup = fkey(v + e);
            #pragma unroll
            for (int d = 1; d < 16; d <<= 1) {
              u32 ol = __shfl_xor(klo, d); if (ol > klo) klo = ol;
              u32 ou = __shfl_xor(kup, d); if (ou > kup) kup = ou;
            }
            if (l15 == 0)
              cst(p.prt + (size_t)nt * 64 + (m * 16 + quad * 4 + r),
                  ((u64)klo << 32) | kup);
          }
        }
      };
      epi(gw, acc0);
      if (two) epi(gw + 2048, acc1);
    }
    gbarF<false>(p, ebF);
    // 3c: threshold T = max lo; rescue every tile with up >= T in exact fp32
    if (wg < NB) {
      const int b = wg;
      char* ms = smem + PBOFF;
      float* hb = (float*)ms;                   // [1024] exact fp32 h
      u64* red = (u64*)(ms + 4096);             // [8]
      u64* gmp = (u64*)(ms + 4160);
      u64* bestp = (u64*)(ms + 4168);
      int* ncp = (int*)(ms + 4176);
      int* list = (int*)(ms + 4192);            // [LCAP]
      for (int i = tid; i < HD; i += TPB) hb[i] = cld(ho + (size_t)i * NB + b);
      if (tid == 0) { *bestp = 0ull; *ncp = 0; }
      __syncthreads();
      u64 mx = 0;
      for (int nt = tid; nt < NTL; nt += TPB) {
        u64 v = cld(p.prt + (size_t)nt * 64 + b);
        if (v > mx) mx = v;
      }
      #pragma unroll
      for (int d = 1; d < 64; d <<= 1) { u64 o = __shfl_xor(mx, d); if (o > mx) mx = o; }
      if (lane == 0) red[wv] = mx;
      __syncthreads();
      if (tid == 0) {
        u64 g = red[0];
        for (int w2 = 1; w2 < 8; w2++) if (red[w2] > g) g = red[w2];
        *gmp = g;
      }
      __syncthreads();
      const u32 thr = (u32)(*gmp >> 32);        // fkey(T), T = max of lo
      for (int nt = tid; nt < NTL; nt += TPB) {
        if ((u32)cld(p.prt + (size_t)nt * 64 + b) >= thr) {   // up >= T
          int ix = atomicAdd(ncp, 1);
          if (ix < LCAP) list[ix] = nt;
        }
      }
      __syncthreads();
      int total = *ncp;
      int nc = total < LCAP ? total : LCAP;
      const int c16 = tid >> 5, seg = tid & 31;
      u64 lb = 0;
      auto rescue = [&](int nt) {
        int v = nt * 16 + c16;
        const float* wr = p.outw + (size_t)v * HD;   // read-only, cached
        float sm = 0.f;
        #pragma unroll 8
        for (int i = 0; i < 32; i++) {
          int k = seg + 32 * i;
          sm = fmaf(hb[k], wr[k], sm);
        }
        #pragma unroll
        for (int d = 1; d < 32; d <<= 1) sm += __shfl_xor(sm, d);
        if (seg == 0) {
          float lg = sm + p.outb[v];
          u64 k2 = ((u64)fkey(lg) << 32) | (~(u32)v);   // ~v: lowest idx wins ties
          if (k2 > lb) lb = k2;
        }
      };
      for (int ci = 0; ci < nc; ci++) rescue(list[ci]);
      if (total > LCAP) {                       // certified fallback
        for (int nt = 0; nt < NTL; nt++)
          if ((u32)cld(p.prt + (size_t)nt * 64 + b) >= thr) rescue(nt);
      }
      if (seg == 0 && lb) atomicMax((unsigned long long*)bestp, lb);
      __syncthreads();
      if (tid == 0) {
        u32 v = ~(u32)(*bestp);
        cst(p.tok + b, (int)v);
        p.out[b * DEC + s] = (float)v;
      }
    }
    gbarF<false>(p, ebF);
  }
}

__global__ void seq2seq_init(u32* bar, float* hTf, float* hTb) {
  int g = blockIdx.x * blockDim.x + threadIdx.x;
  if (g < BAR_WORDS) bar[g] = 0u;
  int n = 2 * HEN * NB;
  for (int i = g; i < n; i += gridDim.x * blockDim.x) { hTf[i] = 0.f; hTb[i] = 0.f; }
}

extern "C" void kernel_launch(void* const* d_in, const int* in_sizes, int n_in,
                              void* d_out, int out_size, void* d_ws, size_t ws_size,
                              hipStream_t stream) {
  char* w = (char*)d_ws;
  size_t off = 0;
  auto carve = [&](size_t n) {
    void* q = w + off;
    off = (off + n + 255) & ~(size_t)255;
    return q;
  };
  P p;
  p.texts = (const int*)d_in[0];
  p.len   = (const int*)d_in[1];
  p.emb   = (const float*)d_in[2];
  p.ewih0 = (const float*)d_in[3];  p.ewhh0 = (const float*)d_in[4];
  p.ebih0 = (const float*)d_in[5];  p.ebhh0 = (const float*)d_in[6];
  p.ewih1 = (const float*)d_in[7];  p.ewhh1 = (const float*)d_in[8];
  p.ebih1 = (const float*)d_in[9];  p.ebhh1 = (const float*)d_in[10];
  p.dwih  = (const float*)d_in[11]; p.dwhh  = (const float*)d_in[12];
  p.dbih  = (const float*)d_in[13]; p.dbhh  = (const float*)d_in[14];
  p.outw  = (const float*)d_in[15]; p.outb  = (const float*)d_in[16];
  p.out   = (float*)d_out;
  p.owbf  = (u16*)carve((size_t)VV * HD * 2);
  p.xT    = (float*)carve((size_t)TT * EE * NB * 4);
  p.hTf   = (float*)carve((size_t)2 * HEN * NB * 4);
  p.hTb   = (float*)carve((size_t)2 * HEN * NB * 4);
  p.hTd   = (float*)carve((size_t)2 * HD * NB * 4);
  p.hbf   = (u16*)carve((size_t)NB * HD * 2);
  p.prt   = (u64*)carve((size_t)NTL * 64 * 8);
  p.tok   = (int*)carve(256);
  p.wn    = (float*)carve((size_t)VV * 4);
  p.bar   = (u32*)carve(BAR_WORDS * 4);
  if (off > ws_size) return;  // workspace too small: fail visibly

  hipFuncSetAttribute((const void*)seq2seq_kernel,
                      hipFuncAttributeMaxDynamicSharedMemorySize, SMEMSZ);

  hipLaunchKernelGGL(seq2seq_init, dim3(64), dim3(256), 0, stream,
                     p.bar, p.hTf, p.hTb);
  void* args[] = { &p };
  hipError_t e = hipLaunchCooperativeKernel((void*)seq2seq_kernel,
                                            dim3(NWG), dim3(TPB), args, SMEMSZ, stream);
  if (e != hipSuccess) {
    seq2seq_kernel<<<dim3(NWG), dim3(TPB), SMEMSZ, stream>>>(p);
  }
}

// Round 4
// 21082.793 us; speedup vs baseline: 1.1694x; 1.0163x over previous
//
#include <hip/hip_runtime.h>
#include <stdint.h>

typedef unsigned int u32;
typedef unsigned long long u64;
typedef unsigned short u16;
typedef __attribute__((ext_vector_type(8))) short s8;
typedef __attribute__((ext_vector_type(4))) float f4;

#define NWG 256
#define TPB 512
#define NB 64      // batch
#define TT 400     // seq len
#define EE 300     // embed dim
#define HEN 512    // encoder hidden
#define HD 1024    // decoder hidden
#define VV 50000   // vocab
#define DEC 80     // decode steps
#define NTL 3125   // VV/16 n-tiles
#define NTLP 3136  // padded row stride for batch-major prt
#define LCAP 512   // rescue list capacity
#define PBOFF 131072           // LDS: [0,128K) hA/enc-weights, [128K,+16K) combine/merge
#define SMEMSZ (PBOFF + 16384)
#define RESC 0.00837f          // 2^-8 * 1.002 * 2.09 safety (bf16 h + bf16 w + fp32 acc)

// barrier state word offsets inside p.bar (each kernel gets its own epoch set)
#define BD_GRP   0      // enc dir barrier: 16 lines x 64
#define BD_ROOT  1024   // + dir*64
#define BD_EPO   1152   // + dir*64
#define BF_GRP   1280   // enc full join: 16 lines x 64
#define BF_ROOT  2304
#define BF_EPO   2368
#define BX_GRP   2432   // dec barriers: 16 lines x 64
#define BX_ROOT  3456
#define BX_EPO   3520
#define BAR_WORDS 3584

struct P {
  const int* texts; const int* len; const float* emb;
  const float* ewih0; const float* ewhh0; const float* ebih0; const float* ebhh0;
  const float* ewih1; const float* ewhh1; const float* ebih1; const float* ebhh1;
  const float* dwih; const float* dwhh; const float* dbih; const float* dbhh;
  const float* outw; const float* outb;
  float* out;
  u16* owbf; float* xT; float* hTf; float* hTb; float* hTd; u16* hbf;
  u64* prt; int* tok; float* wn;
  u32* bar;
};

// ---- coherent (agent-scope, cache-bypassing) accessors for MUTABLE cross-wg
// data. sc0/sc1 ops hit the coherence point directly -> no cache-wide fences,
// read-only data stays L2-resident.
__device__ __forceinline__ float cld(const float* a) {
  return __hip_atomic_load(const_cast<float*>(a), __ATOMIC_RELAXED, __HIP_MEMORY_SCOPE_AGENT);
}
__device__ __forceinline__ void cst(float* a, float v) {
  __hip_atomic_store(a, v, __ATOMIC_RELAXED, __HIP_MEMORY_SCOPE_AGENT);
}
__device__ __forceinline__ u64 cld(const u64* a) {
  return __hip_atomic_load(const_cast<u64*>(a), __ATOMIC_RELAXED, __HIP_MEMORY_SCOPE_AGENT);
}
__device__ __forceinline__ void cst(u64* a, u64 v) {
  __hip_atomic_store(a, v, __ATOMIC_RELAXED, __HIP_MEMORY_SCOPE_AGENT);
}
__device__ __forceinline__ int cld(const int* a) {
  return __hip_atomic_load(const_cast<int*>(a), __ATOMIC_RELAXED, __HIP_MEMORY_SCOPE_AGENT);
}
__device__ __forceinline__ void cst(int* a, int v) {
  __hip_atomic_store(a, v, __ATOMIC_RELAXED, __HIP_MEMORY_SCOPE_AGENT);
}
__device__ __forceinline__ void cst(u16* a, u16 v) {
  __hip_atomic_store(a, v, __ATOMIC_RELAXED, __HIP_MEMORY_SCOPE_AGENT);
}

// Tree barrier: groups of 16 arrive on a private line; last of group hits root;
// last root sets epoch. __syncthreads drains vmcnt, so all of this wg's
// coherent stores are at the coherence point before tid0 arrives.
__device__ __forceinline__ void gbarx(u32* grp, u32* root, u32* epo,
                                      u32 e, u32 gsz, u32 nroot) {
  __syncthreads();
  if (threadIdx.x == 0) {
    u32 old = __hip_atomic_fetch_add(grp, 1u, __ATOMIC_RELAXED, __HIP_MEMORY_SCOPE_AGENT);
    if (old == e * gsz + (gsz - 1u)) {
      u32 r = __hip_atomic_fetch_add(root, 1u, __ATOMIC_RELAXED, __HIP_MEMORY_SCOPE_AGENT);
      if (r == e * nroot + (nroot - 1u))
        __hip_atomic_store(epo, e + 1u, __ATOMIC_RELAXED, __HIP_MEMORY_SCOPE_AGENT);
    }
    while (__hip_atomic_load(epo, __ATOMIC_RELAXED, __HIP_MEMORY_SCOPE_AGENT) < e + 1u)
      __builtin_amdgcn_s_sleep(8);
  }
  __syncthreads();
}

__device__ __forceinline__ u32 fkey(float v) {
  u32 u = __float_as_uint(v);
  return (u & 0x80000000u) ? ~u : (u | 0x80000000u);
}
__device__ __forceinline__ u16 f2bf(float f) {   // RNE fp32->bf16
  u32 u = __float_as_uint(f);
  u32 r = u + 0x7FFFu + ((u >> 16) & 1u);
  return (u16)(r >> 16);
}
__device__ __forceinline__ float sigm(float x) { return 1.f / (1.f + expf(-x)); }

// ---- shared GRU epilogue: two-stage partial combine in 16KB LDS + activations
__device__ __forceinline__ void gru_combine_epi(
    char* smem, const f4& ar, const f4& az, const f4& ax, const f4& ah,
    int jjb, int HL, const float* bih, const float* bhh,
    const float* hc, float* ho, int mask_t, const int* lenp, u16* hbf_out)
{
  const int tid = threadIdx.x, lane = tid & 63, wv = tid >> 6;
  float* pb = (float*)(smem + PBOFF);     // [4][16][64]
  const int wl = wv & 3;
  if (wv < 4) {
    #pragma unroll
    for (int j = 0; j < 4; j++) {
      pb[((wl * 16 + j * 4 + 0) * 64) + lane] = ar[j];
      pb[((wl * 16 + j * 4 + 1) * 64) + lane] = az[j];
      pb[((wl * 16 + j * 4 + 2) * 64) + lane] = ax[j];
      pb[((wl * 16 + j * 4 + 3) * 64) + lane] = ah[j];
    }
  }
  __syncthreads();
  if (wv >= 4) {
    #pragma unroll
    for (int j = 0; j < 4; j++) {
      pb[((wl * 16 + j * 4 + 0) * 64) + lane] += ar[j];
      pb[((wl * 16 + j * 4 + 1) * 64) + lane] += az[j];
      pb[((wl * 16 + j * 4 + 2) * 64) + lane] += ax[j];
      pb[((wl * 16 + j * 4 + 3) * 64) + lane] += ah[j];
    }
  }
  __syncthreads();
  if (tid < 256) {
    int b = tid & 63, j = tid >> 6;
    int jj = jjb + j;
    float r = 0, z = 0, xn = 0, hn = 0;
    #pragma unroll
    for (int w = 0; w < 4; w++) {
      int base = ((w * 16 + j * 4) * 64) + b;
      r  += pb[base];
      z  += pb[base + 64];
      xn += pb[base + 128];
      hn += pb[base + 192];
    }
    r = sigm(r + bih[jj] + bhh[jj]);
    z = sigm(z + bih[HL + jj] + bhh[HL + jj]);
    float nn = tanhf(xn + bih[2 * HL + jj] + r * (hn + bhh[2 * HL + jj]));
    float hold = cld(hc + (size_t)jj * NB + b);
    float hv = (1.f - z) * nn + z * hold;
    if (lenp && mask_t >= lenp[b]) hv = hold;
    cst(ho + (size_t)jj * NB + b, hv);
    if (hbf_out) cst(hbf_out + (size_t)b * HD + jj, f2bf(hv));
  }
}

// Encoder step: weights pre-staged in LDS [k][12] (gate-major within 48B row)
__device__ __forceinline__ void gru_enc(
    char* smem, int jjb, const float* xsrc,
    const float* bih, const float* bhh,
    const float* __restrict__ hc, float* ho, int tt, const int* lenp)
{
  const int tid = threadIdx.x, lane = tid & 63, wv = tid >> 6;
  const float* lw = (const float*)smem;
  const int KT = EE + HEN;
  const int vs = (wv * KT) >> 3, ve = ((wv + 1) * KT) >> 3;
  f4 ar = {0,0,0,0}, az = {0,0,0,0}, ax = {0,0,0,0}, ah = {0,0,0,0};
  int xe = ve < EE ? ve : EE;
  #pragma unroll 2
  for (int k = vs; k < xe; k++) {
    float xv = xsrc[(size_t)k * NB + lane];        // read-only, cached
    f4 w0 = *(const f4*)(lw + k * 12);
    f4 w1 = *(const f4*)(lw + k * 12 + 4);
    f4 w2 = *(const f4*)(lw + k * 12 + 8);
    ar += xv * w0; az += xv * w1; ax += xv * w2;
  }
  int hs = vs > EE ? vs : EE;
  #pragma unroll 2
  for (int k = hs; k < ve; k++) {
    float hv = cld(hc + (size_t)(k - EE) * NB + lane);   // mutable, coherent
    f4 w0 = *(const f4*)(lw + k * 12);
    f4 w1 = *(const f4*)(lw + k * 12 + 4);
    f4 w2 = *(const f4*)(lw + k * 12 + 8);
    ar += hv * w0; az += hv * w1; ah += hv * w2;
  }
  gru_combine_epi(smem, ar, az, ax, ah, jjb, HEN, bih, bhh, hc, ho, tt, lenp, nullptr);
}

// Decoder step: weights from global (cached, L2-resident), x = emb[tok]
__device__ __forceinline__ void gru_dec(
    const P& p, char* smem, int jjb,
    const float* __restrict__ hc, float* ho)
{
  const int tid = threadIdx.x, lane = tid & 63, wv = tid >> 6;
  const float* wih = p.dwih; const float* whh = p.dwhh;
  const int KT = EE + HD;
  const int vs = (wv * KT) >> 3, ve = ((wv + 1) * KT) >> 3;
  f4 ar = {0,0,0,0}, az = {0,0,0,0}, ax = {0,0,0,0}, ah = {0,0,0,0};
  int xe = ve < EE ? ve : EE;
  if (vs < EE) {
    const float* xr = p.emb + (size_t)cld(p.tok + lane) * EE;
    for (int k = vs; k < xe; k++) {
      float xv = xr[k];
      #pragma unroll
      for (int j = 0; j < 4; j++) {
        int jj = jjb + j;
        ar[j] = fmaf(xv, wih[(size_t)jj * EE + k], ar[j]);
        az[j] = fmaf(xv, wih[(size_t)(HD + jj) * EE + k], az[j]);
        ax[j] = fmaf(xv, wih[(size_t)(2 * HD + jj) * EE + k], ax[j]);
      }
    }
  }
  int hs = vs - EE; if (hs < 0) hs = 0;
  int he = ve - EE;
  for (int k = hs; k < he; k++) {
    float hv = cld(hc + (size_t)k * NB + lane);
    #pragma unroll
    for (int j = 0; j < 4; j++) {
      int jj = jjb + j;
      ar[j] = fmaf(hv, whh[(size_t)jj * HD + k], ar[j]);
      az[j] = fmaf(hv, whh[(size_t)(HD + jj) * HD + k], az[j]);
      ah[j] = fmaf(hv, whh[(size_t)(2 * HD + jj) * HD + k], ah[j]);
    }
  }
  gru_combine_epi(smem, ar, az, ax, ah, jjb, HD, p.dbih, p.dbhh,
                  hc, ho, -1, nullptr, p.hbf);
}

// ================= kernel 1: one-time prep (plain dispatch) =================
__global__ void __launch_bounds__(TPB, 2) prep_kernel(P p) {
  const int wg = blockIdx.x, tid = threadIdx.x;
  const int lane = tid & 63, wv = tid >> 6;
  const int gtid = wg * TPB + tid;
  // out_w -> bf16 copy + per-row L2 norm (certified rescue bound)
  int gwv = wg * 8 + wv;
  for (int v = gwv; v < VV; v += 2048) {
    const float* wr = p.outw + (size_t)v * HD + lane * 16;
    u16* dst = p.owbf + (size_t)v * HD + lane * 16;
    float sa = 0.f;
    u32 pk[8];
    #pragma unroll
    for (int q = 0; q < 4; q++) {
      float4 f = *(const float4*)(wr + q * 4);
      sa += f.x * f.x + f.y * f.y + f.z * f.z + f.w * f.w;
      pk[q * 2 + 0] = (u32)f2bf(f.x) | ((u32)f2bf(f.y) << 16);
      pk[q * 2 + 1] = (u32)f2bf(f.z) | ((u32)f2bf(f.w) << 16);
    }
    *(uint4*)(dst)     = make_uint4(pk[0], pk[1], pk[2], pk[3]);
    *(uint4*)(dst + 8) = make_uint4(pk[4], pk[5], pk[6], pk[7]);
    #pragma unroll
    for (int d = 1; d < 64; d <<= 1) sa += __shfl_xor(sa, d);
    if (lane == 0) p.wn[v] = sqrtf(sa);
  }
  // gather+transpose encoder inputs: xT[t][k][b] = emb[texts[b][t]][k]
  const long long tot = (long long)TT * NB * EE;
  for (long long i = gtid; i < tot; i += (long long)NWG * TPB) {
    int t = (int)(i / (NB * EE));
    int rr = (int)(i % (NB * EE));
    int b2 = rr / EE, k = rr % EE;
    float v = p.emb[(size_t)p.texts[b2 * TT + t] * EE + k];
    p.xT[((size_t)t * EE + k) * NB + b2] = v;
  }
}

// ================= kernel 2: bidirectional encoder (cooperative) ============
__global__ void __launch_bounds__(TPB, 1) enc_kernel(P p) {
  extern __shared__ __align__(16) char smem[];
  const int wg = blockIdx.x, tid = threadIdx.x;
  const int lane = tid & 63, wv = tid >> 6;
  const int gtid = wg * TPB + tid;
  u32 ebD = 0, ebF = 0;
  const int dir = wg >> 7;           // wgs 0..127 fwd, 128..255 bwd
  const int ejjb = (wg & 127) * 4;

  // stage this wg's encoder weight slice into LDS: lw[k][g*4+j]
  {
    const float* wih = dir ? p.ewih1 : p.ewih0;
    const float* whh = dir ? p.ewhh1 : p.ewhh0;
    float* lw = (float*)smem;
    for (int c = wv; c < 12; c += 8) {
      int g = c >> 2, j = c & 3;
      const float* sx = wih + (size_t)(g * HEN + ejjb + j) * EE;
      for (int k = lane; k < EE; k += 64) lw[k * 12 + c] = sx[k];
      const float* sh = whh + (size_t)(g * HEN + ejjb + j) * HEN;
      for (int k = lane; k < HEN; k += 64) lw[(EE + k) * 12 + c] = sh[k];
    }
  }
  __syncthreads();

  {
    const float* bih = dir ? p.ebih1 : p.ebih0;
    const float* bhh = dir ? p.ebhh1 : p.ebhh0;
    float* hbase = dir ? p.hTb : p.hTf;
    for (int t = 0; t < TT; t++) {
      int te = dir ? (TT - 1 - t) : t;
      const float* hc = hbase + (size_t)(t & 1) * HEN * NB;
      float* ho = hbase + (size_t)((t + 1) & 1) * HEN * NB;
      gru_enc(smem, ejjb, p.xT + (size_t)te * EE * NB, bih, bhh, hc, ho, te, p.len);
      gbarx(p.bar + BD_GRP + ((wg >> 4) << 6),
            p.bar + BD_ROOT + dir * 64, p.bar + BD_EPO + dir * 64, ebD++, 16u, 8u);
    }
  }
  // join fwd+bwd, then concat + tok init
  gbarx(p.bar + BF_GRP + ((wg >> 4) << 6),
        p.bar + BF_ROOT, p.bar + BF_EPO, ebF++, 16u, 16u);
  for (int i = gtid; i < HD * NB; i += NWG * TPB) {
    int k = i / NB, b2 = i % NB;
    float v = (k < HEN) ? cld(p.hTf + (size_t)k * NB + b2)
                        : cld(p.hTb + (size_t)(k - HEN) * NB + b2);
    cst(p.hTd + i, v);
  }
  if (gtid < NB) cst(p.tok + gtid, 1);   // sos
}

// ================= kernel 3: decoder (cooperative) ==========================
__global__ void __launch_bounds__(TPB, 1) dec_kernel(P p) {
  extern __shared__ __align__(16) char smem[];
  const int wg = blockIdx.x, tid = threadIdx.x;
  const int lane = tid & 63, wv = tid >> 6;
  u32 ebX = 0;

  for (int s = 0; s < DEC; s++) {
    const float* hc = p.hTd + (size_t)(s & 1) * HD * NB;
    float* ho = p.hTd + (size_t)((s + 1) & 1) * HD * NB;
    // 3a: GRU step (emits bf16 row-major h)
    gru_dec(p, smem, wg * 4, hc, ho);
    gbarx(p.bar + BX_GRP + ((wg >> 4) << 6),
          p.bar + BX_ROOT, p.bar + BX_EPO, ebX++, 16u, 16u);
    // 3b: bf16 MFMA logits + per-tile certified (lo,up) interval keys.
    {
      u16* hA = (u16*)smem;                 // [64][128 chunks of 16B], swizzled
      float* hsq = (float*)(smem + PBOFF);  // [64]
      const int l15 = lane & 15, quad = lane >> 4;
      const int gw = wg * 8 + wv;
      const bool two = (gw + 2048) < NTL;
      if (tid < 64) hsq[tid] = 0.f;
      __syncthreads();
      const u64* hb64 = (const u64*)p.hbf;        // 256 u64 per row
      u64* hA64 = (u64*)hA;
      for (int i = tid; i < 16384; i += TPB) {    // stage full hbf + ||h||^2
        int r = i >> 8, c = i & 255;
        u64 q = cld(hb64 + (size_t)r * 256 + c);  // coherent (mutable)
        int cc = c >> 1;                          // 16B chunk index
        hA64[(size_t)r * 256 + ((cc ^ (r & 7)) * 2) + (c & 1)] = q;
        u32 uu[2] = {(u32)q, (u32)(q >> 32)};
        float sq = 0.f;
        #pragma unroll
        for (int t2 = 0; t2 < 2; t2++) {
          float lo = __uint_as_float(uu[t2] << 16);
          float hi = __uint_as_float(uu[t2] & 0xffff0000u);
          sq = fmaf(lo, lo, fmaf(hi, hi, sq));
        }
        atomicAdd(&hsq[r], sq);
      }
      __syncthreads();
      f4 acc0[4], acc1[4];
      #pragma unroll
      for (int m = 0; m < 4; m++) {
        #pragma unroll
        for (int r = 0; r < 4; r++) { acc0[m][r] = 0.f; acc1[m][r] = 0.f; }
      }
      const u16* bp0 = p.owbf + (size_t)(gw * 16 + l15) * HD + quad * 8;  // cached
      const u16* bp1 = bp0 + (size_t)2048 * 16 * HD;
      const int x7 = l15 & 7;
      const u16* hrow = hA + l15 * 1024;
      #pragma unroll 4
      for (int kc = 0; kc < 32; kc++) {
        int ci = ((kc * 4 + quad) ^ x7) * 8;
        s8 b0 = *(const s8*)(bp0 + kc * 32);
        s8 a0 = *(const s8*)(hrow + ci);
        s8 a1 = *(const s8*)(hrow + 16384 + ci);
        s8 a2 = *(const s8*)(hrow + 32768 + ci);
        s8 a3 = *(const s8*)(hrow + 49152 + ci);
        acc0[0] = __builtin_amdgcn_mfma_f32_16x16x32_bf16(a0, b0, acc0[0], 0, 0, 0);
        acc0[1] = __builtin_amdgcn_mfma_f32_16x16x32_bf16(a1, b0, acc0[1], 0, 0, 0);
        acc0[2] = __builtin_amdgcn_mfma_f32_16x16x32_bf16(a2, b0, acc0[2], 0, 0, 0);
        acc0[3] = __builtin_amdgcn_mfma_f32_16x16x32_bf16(a3, b0, acc0[3], 0, 0, 0);
        if (two) {
          s8 b1 = *(const s8*)(bp1 + kc * 32);
          acc1[0] = __builtin_amdgcn_mfma_f32_16x16x32_bf16(a0, b1, acc1[0], 0, 0, 0);
          acc1[1] = __builtin_amdgcn_mfma_f32_16x16x32_bf16(a1, b1, acc1[1], 0, 0, 0);
          acc1[2] = __builtin_amdgcn_mfma_f32_16x16x32_bf16(a2, b1, acc1[2], 0, 0, 0);
          acc1[3] = __builtin_amdgcn_mfma_f32_16x16x32_bf16(a3, b1, acc1[3], 0, 0, 0);
        }
      }
      float hroot[4][4];
      #pragma unroll
      for (int m = 0; m < 4; m++)
        #pragma unroll
        for (int r = 0; r < 4; r++)
          hroot[m][r] = sqrtf(hsq[m * 16 + quad * 4 + r]);
      auto epi = [&](int nt, f4* acc) {
        int col = nt * 16 + l15;
        float bias = p.outb[col];
        float wnc = p.wn[col];
        #pragma unroll
        for (int m = 0; m < 4; m++) {
          #pragma unroll
          for (int r = 0; r < 4; r++) {
            float v = acc[m][r] + bias;
            float e = RESC * hroot[m][r] * wnc + 1e-5f;
            u32 klo = fkey(v - e), kup = fkey(v + e);
            #pragma unroll
            for (int d = 1; d < 16; d <<= 1) {
              u32 ol = __shfl_xor(klo, d); if (ol > klo) klo = ol;
              u32 ou = __shfl_xor(kup, d); if (ou > kup) kup = ou;
            }
            if (l15 == 0)   // batch-major: prt[row][nt], dense per-batch scans
              cst(p.prt + (size_t)(m * 16 + quad * 4 + r) * NTLP + nt,
                  ((u64)klo << 32) | kup);
          }
        }
      };
      epi(gw, acc0);
      if (two) epi(gw + 2048, acc1);
    }
    gbarx(p.bar + BX_GRP + ((wg >> 4) << 6),
          p.bar + BX_ROOT, p.bar + BX_EPO, ebX++, 16u, 16u);
    // 3c: threshold T = max lo; rescue every tile with up >= T in exact fp32
    if (wg < NB) {
      const int b = wg;
      char* ms = smem + PBOFF;
      float* hb = (float*)ms;                   // [1024] exact fp32 h
      u64* red = (u64*)(ms + 4096);             // [8]
      u64* gmp = (u64*)(ms + 4160);
      u64* bestp = (u64*)(ms + 4168);
      int* ncp = (int*)(ms + 4176);
      int* list = (int*)(ms + 4192);            // [LCAP]
      for (int i = tid; i < HD; i += TPB) hb[i] = cld(ho + (size_t)i * NB + b);
      if (tid == 0) { *bestp = 0ull; *ncp = 0; }
      __syncthreads();
      // pass 1: dense coalesced scan of this batch's prt row, values cached in regs
      u64 pv[7];
      u64 mx = 0;
      #pragma unroll
      for (int i = 0; i < 7; i++) {
        int nt = tid + i * TPB;
        pv[i] = (nt < NTL) ? cld(p.prt + (size_t)b * NTLP + nt) : 0ull;
        if (pv[i] > mx) mx = pv[i];
      }
      #pragma unroll
      for (int d = 1; d < 64; d <<= 1) { u64 o = __shfl_xor(mx, d); if (o > mx) mx = o; }
      if (lane == 0) red[wv] = mx;
      __syncthreads();
      if (tid == 0) {
        u64 g = red[0];
        for (int w2 = 1; w2 < 8; w2++) if (red[w2] > g) g = red[w2];
        *gmp = g;
      }
      __syncthreads();
      const u32 thr = (u32)(*gmp >> 32);        // fkey(T), T = max of lo
      // pass 2: filter from registers (no memory)
      #pragma unroll
      for (int i = 0; i < 7; i++) {
        if ((u32)pv[i] >= thr) {                // up >= T (nt<NTL implied: pv=0 else)
          int ix = atomicAdd(ncp, 1);
          if (ix < LCAP) list[ix] = tid + i * TPB;
        }
      }
      __syncthreads();
      int total = *ncp;
      int nc = total < LCAP ? total : LCAP;
      const int c16 = tid >> 5, seg = tid & 31;
      u64 lb = 0;
      auto rescue = [&](int nt) {
        int v = nt * 16 + c16;
        const float* wr = p.outw + (size_t)v * HD;   // read-only, cached
        float sm = 0.f;
        #pragma unroll 8
        for (int i = 0; i < 32; i++) {
          int k = seg + 32 * i;
          sm = fmaf(hb[k], wr[k], sm);
        }
        #pragma unroll
        for (int d = 1; d < 32; d <<= 1) sm += __shfl_xor(sm, d);
        if (seg == 0) {
          float lg = sm + p.outb[v];
          u64 k2 = ((u64)fkey(lg) << 32) | (~(u32)v);   // ~v: lowest idx wins ties
          if (k2 > lb) lb = k2;
        }
      };
      for (int ci = 0; ci < nc; ci++) rescue(list[ci]);
      if (total > LCAP) {                       // certified fallback
        for (int nt = 0; nt < NTL; nt++)
          if ((u32)cld(p.prt + (size_t)b * NTLP + nt) >= thr) rescue(nt);
      }
      if (seg == 0 && lb) atomicMax((unsigned long long*)bestp, lb);
      __syncthreads();
      if (tid == 0) {
        u32 v = ~(u32)(*bestp);
        cst(p.tok + b, (int)v);
        p.out[b * DEC + s] = (float)v;
      }
    }
    gbarx(p.bar + BX_GRP + ((wg >> 4) << 6),
          p.bar + BX_ROOT, p.bar + BX_EPO, ebX++, 16u, 16u);
  }
}

__global__ void seq2seq_init(u32* bar, float* hTf, float* hTb) {
  int g = blockIdx.x * blockDim.x + threadIdx.x;
  if (g < BAR_WORDS) bar[g] = 0u;
  int n = 2 * HEN * NB;
  for (int i = g; i < n; i += gridDim.x * blockDim.x) { hTf[i] = 0.f; hTb[i] = 0.f; }
}

extern "C" void kernel_launch(void* const* d_in, const int* in_sizes, int n_in,
                              void* d_out, int out_size, void* d_ws, size_t ws_size,
                              hipStream_t stream) {
  char* w = (char*)d_ws;
  size_t off = 0;
  auto carve = [&](size_t n) {
    void* q = w + off;
    off = (off + n + 255) & ~(size_t)255;
    return q;
  };
  P p;
  p.texts = (const int*)d_in[0];
  p.len   = (const int*)d_in[1];
  p.emb   = (const float*)d_in[2];
  p.ewih0 = (const float*)d_in[3];  p.ewhh0 = (const float*)d_in[4];
  p.ebih0 = (const float*)d_in[5];  p.ebhh0 = (const float*)d_in[6];
  p.ewih1 = (const float*)d_in[7];  p.ewhh1 = (const float*)d_in[8];
  p.ebih1 = (const float*)d_in[9];  p.ebhh1 = (const float*)d_in[10];
  p.dwih  = (const float*)d_in[11]; p.dwhh  = (const float*)d_in[12];
  p.dbih  = (const float*)d_in[13]; p.dbhh  = (const float*)d_in[14];
  p.outw  = (const float*)d_in[15]; p.outb  = (const float*)d_in[16];
  p.out   = (float*)d_out;
  p.owbf  = (u16*)carve((size_t)VV * HD * 2);
  p.xT    = (float*)carve((size_t)TT * EE * NB * 4);
  p.hTf   = (float*)carve((size_t)2 * HEN * NB * 4);
  p.hTb   = (float*)carve((size_t)2 * HEN * NB * 4);
  p.hTd   = (float*)carve((size_t)2 * HD * NB * 4);
  p.hbf   = (u16*)carve((size_t)NB * HD * 2);
  p.prt   = (u64*)carve((size_t)NB * NTLP * 8);
  p.tok   = (int*)carve(256);
  p.wn    = (float*)carve((size_t)VV * 4);
  p.bar   = (u32*)carve(BAR_WORDS * 4);
  if (off > ws_size) return;  // workspace too small: fail visibly

  hipFuncSetAttribute((const void*)enc_kernel,
                      hipFuncAttributeMaxDynamicSharedMemorySize, SMEMSZ);
  hipFuncSetAttribute((const void*)dec_kernel,
                      hipFuncAttributeMaxDynamicSharedMemorySize, SMEMSZ);

  hipLaunchKernelGGL(seq2seq_init, dim3(64), dim3(256), 0, stream,
                     p.bar, p.hTf, p.hTb);
  hipLaunchKernelGGL(prep_kernel, dim3(NWG), dim3(TPB), 0, stream, p);
  void* args[] = { &p };
  hipError_t e = hipLaunchCooperativeKernel((void*)enc_kernel,
                                            dim3(NWG), dim3(TPB), args, SMEMSZ, stream);
  if (e != hipSuccess) {
    enc_kernel<<<dim3(NWG), dim3(TPB), SMEMSZ, stream>>>(p);
  }
  e = hipLaunchCooperativeKernel((void*)dec_kernel,
                                 dim3(NWG), dim3(TPB), args, SMEMSZ, stream);
  if (e != hipSuccess) {
    dec_kernel<<<dim3(NWG), dim3(TPB), SMEMSZ, stream>>>(p);
  }
}

// Round 5
// 17982.848 us; speedup vs baseline: 1.3710x; 1.1724x over previous
//
#include <hip/hip_runtime.h>
#include <stdint.h>

typedef unsigned int u32;
typedef unsigned long long u64;
typedef unsigned short u16;
typedef __attribute__((ext_vector_type(8))) short s8;
typedef __attribute__((ext_vector_type(4))) float f4;

#define NWG 256
#define TPB 512
#define NB 64      // batch
#define TT 400     // seq len
#define EE 300     // embed dim
#define HEN 512    // encoder hidden
#define HD 1024    // decoder hidden
#define VV 50000   // vocab
#define DEC 80     // decode steps
#define NTL 3125   // VV/16 n-tiles
#define NTLP 3136  // padded row stride for batch-major prt
#define LCAP 512   // rescue list capacity
#define PBOFF 131072           // LDS: [0,128K) hA/enc-weights, [128K,+16K) combine/merge
#define SMEMSZ (PBOFF + 16384)
#define RESC 0.00837f          // 2^-8 * 1.002 * 2.09 safety (bf16 h + bf16 w + fp32 acc)

// barrier state word offsets inside p.bar (each kernel gets its own epoch set)
#define BD_GRP   0      // enc dir barrier: 16 lines x 64
#define BD_ROOT  1024   // + dir*64
#define BD_EPO   1152   // + dir*64
#define BF_GRP   1280   // enc full join: 16 lines x 64
#define BF_ROOT  2304
#define BF_EPO   2368
#define BX_GRP   2432   // dec barriers: 16 lines x 64
#define BX_ROOT  3456
#define BX_EPO   3520
#define BAR_WORDS 3584

struct P {
  const int* texts; const int* len; const float* emb;
  const float* ewih0; const float* ewhh0; const float* ebih0; const float* ebhh0;
  const float* ewih1; const float* ewhh1; const float* ebih1; const float* ebhh1;
  const float* dwih; const float* dwhh; const float* dbih; const float* dbhh;
  const float* outw; const float* outb;
  float* out;
  u16* owbf; float* xT; float* hTf; float* hTb; float* hTd; u16* hbf;
  u64* prt; int* tok; float* wn;
  u32* bar;
};

// ---- coherent (agent-scope, cache-bypassing) accessors for MUTABLE cross-wg
// data. sc0/sc1 ops hit the coherence point directly -> no cache-wide fences,
// read-only data stays L2-resident. NOTE: these have full LLC latency and are
// never cached -> callers MUST batch independent cld's for MLP.
__device__ __forceinline__ float cld(const float* a) {
  return __hip_atomic_load(const_cast<float*>(a), __ATOMIC_RELAXED, __HIP_MEMORY_SCOPE_AGENT);
}
__device__ __forceinline__ void cst(float* a, float v) {
  __hip_atomic_store(a, v, __ATOMIC_RELAXED, __HIP_MEMORY_SCOPE_AGENT);
}
__device__ __forceinline__ u64 cld(const u64* a) {
  return __hip_atomic_load(const_cast<u64*>(a), __ATOMIC_RELAXED, __HIP_MEMORY_SCOPE_AGENT);
}
__device__ __forceinline__ void cst(u64* a, u64 v) {
  __hip_atomic_store(a, v, __ATOMIC_RELAXED, __HIP_MEMORY_SCOPE_AGENT);
}
__device__ __forceinline__ int cld(const int* a) {
  return __hip_atomic_load(const_cast<int*>(a), __ATOMIC_RELAXED, __HIP_MEMORY_SCOPE_AGENT);
}
__device__ __forceinline__ void cst(int* a, int v) {
  __hip_atomic_store(a, v, __ATOMIC_RELAXED, __HIP_MEMORY_SCOPE_AGENT);
}
__device__ __forceinline__ void cst(u16* a, u16 v) {
  __hip_atomic_store(a, v, __ATOMIC_RELAXED, __HIP_MEMORY_SCOPE_AGENT);
}

// Tree barrier: groups of 16 arrive on a private line; last of group hits root;
// last root sets epoch. __syncthreads drains vmcnt, so all of this wg's
// coherent stores are at the coherence point before tid0 arrives.
__device__ __forceinline__ void gbarx(u32* grp, u32* root, u32* epo,
                                      u32 e, u32 gsz, u32 nroot) {
  __syncthreads();
  if (threadIdx.x == 0) {
    u32 old = __hip_atomic_fetch_add(grp, 1u, __ATOMIC_RELAXED, __HIP_MEMORY_SCOPE_AGENT);
    if (old == e * gsz + (gsz - 1u)) {
      u32 r = __hip_atomic_fetch_add(root, 1u, __ATOMIC_RELAXED, __HIP_MEMORY_SCOPE_AGENT);
      if (r == e * nroot + (nroot - 1u))
        __hip_atomic_store(epo, e + 1u, __ATOMIC_RELAXED, __HIP_MEMORY_SCOPE_AGENT);
    }
    while (__hip_atomic_load(epo, __ATOMIC_RELAXED, __HIP_MEMORY_SCOPE_AGENT) < e + 1u)
      __builtin_amdgcn_s_sleep(8);
  }
  __syncthreads();
}

__device__ __forceinline__ u32 fkey(float v) {
  u32 u = __float_as_uint(v);
  return (u & 0x80000000u) ? ~u : (u | 0x80000000u);
}
__device__ __forceinline__ u16 f2bf(float f) {   // RNE fp32->bf16
  u32 u = __float_as_uint(f);
  u32 r = u + 0x7FFFu + ((u >> 16) & 1u);
  return (u16)(r >> 16);
}
__device__ __forceinline__ float sigm(float x) { return 1.f / (1.f + expf(-x)); }

// ---- shared GRU epilogue: two-stage partial combine in 16KB LDS + activations
__device__ __forceinline__ void gru_combine_epi(
    char* smem, const f4& ar, const f4& az, const f4& ax, const f4& ah,
    int jjb, int HL, const float* bih, const float* bhh,
    const float* hc, float* ho, int mask_t, const int* lenp, u16* hbf_out)
{
  const int tid = threadIdx.x, lane = tid & 63, wv = tid >> 6;
  float* pb = (float*)(smem + PBOFF);     // [4][16][64]
  const int wl = wv & 3;
  if (wv < 4) {
    #pragma unroll
    for (int j = 0; j < 4; j++) {
      pb[((wl * 16 + j * 4 + 0) * 64) + lane] = ar[j];
      pb[((wl * 16 + j * 4 + 1) * 64) + lane] = az[j];
      pb[((wl * 16 + j * 4 + 2) * 64) + lane] = ax[j];
      pb[((wl * 16 + j * 4 + 3) * 64) + lane] = ah[j];
    }
  }
  __syncthreads();
  if (wv >= 4) {
    #pragma unroll
    for (int j = 0; j < 4; j++) {
      pb[((wl * 16 + j * 4 + 0) * 64) + lane] += ar[j];
      pb[((wl * 16 + j * 4 + 1) * 64) + lane] += az[j];
      pb[((wl * 16 + j * 4 + 2) * 64) + lane] += ax[j];
      pb[((wl * 16 + j * 4 + 3) * 64) + lane] += ah[j];
    }
  }
  __syncthreads();
  if (tid < 256) {
    int b = tid & 63, j = tid >> 6;
    int jj = jjb + j;
    float r = 0, z = 0, xn = 0, hn = 0;
    #pragma unroll
    for (int w = 0; w < 4; w++) {
      int base = ((w * 16 + j * 4) * 64) + b;
      r  += pb[base];
      z  += pb[base + 64];
      xn += pb[base + 128];
      hn += pb[base + 192];
    }
    r = sigm(r + bih[jj] + bhh[jj]);
    z = sigm(z + bih[HL + jj] + bhh[HL + jj]);
    float nn = tanhf(xn + bih[2 * HL + jj] + r * (hn + bhh[2 * HL + jj]));
    float hold = cld(hc + (size_t)jj * NB + b);
    float hv = (1.f - z) * nn + z * hold;
    if (lenp && mask_t >= lenp[b]) hv = hold;
    cst(ho + (size_t)jj * NB + b, hv);
    if (hbf_out) cst(hbf_out + (size_t)b * HD + jj, f2bf(hv));
  }
}

// Encoder step: weights pre-staged in LDS [k][12] (gate-major within 48B row).
// Coherent h-loads batched x8 for memory-level parallelism (latency-chain fix).
__device__ __forceinline__ void gru_enc(
    char* smem, int jjb, const float* xsrc,
    const float* bih, const float* bhh,
    const float* __restrict__ hc, float* ho, int tt, const int* lenp)
{
  const int tid = threadIdx.x, lane = tid & 63, wv = tid >> 6;
  const float* lw = (const float*)smem;
  const int KT = EE + HEN;
  const int vs = (wv * KT) >> 3, ve = ((wv + 1) * KT) >> 3;
  f4 ar = {0,0,0,0}, az = {0,0,0,0}, ax = {0,0,0,0}, ah = {0,0,0,0};
  const int xe = ve < EE ? ve : EE;
  int k = vs;
  for (; k + 8 <= xe; k += 8) {
    float xv[8];
    #pragma unroll
    for (int u = 0; u < 8; u++) xv[u] = xsrc[(size_t)(k + u) * NB + lane];
    #pragma unroll
    for (int u = 0; u < 8; u++) {
      const float* wp = lw + (k + u) * 12;
      f4 w0 = *(const f4*)wp; f4 w1 = *(const f4*)(wp + 4); f4 w2 = *(const f4*)(wp + 8);
      ar += xv[u] * w0; az += xv[u] * w1; ax += xv[u] * w2;
    }
  }
  for (; k < xe; k++) {
    float xv = xsrc[(size_t)k * NB + lane];
    const float* wp = lw + k * 12;
    f4 w0 = *(const f4*)wp; f4 w1 = *(const f4*)(wp + 4); f4 w2 = *(const f4*)(wp + 8);
    ar += xv * w0; az += xv * w1; ax += xv * w2;
  }
  k = vs > EE ? vs : EE;
  for (; k + 8 <= ve; k += 8) {
    float hv[8];
    #pragma unroll
    for (int u = 0; u < 8; u++) hv[u] = cld(hc + (size_t)(k + u - EE) * NB + lane);
    #pragma unroll
    for (int u = 0; u < 8; u++) {
      const float* wp = lw + (k + u) * 12;
      f4 w0 = *(const f4*)wp; f4 w1 = *(const f4*)(wp + 4); f4 w2 = *(const f4*)(wp + 8);
      ar += hv[u] * w0; az += hv[u] * w1; ah += hv[u] * w2;
    }
  }
  for (; k < ve; k++) {
    float hv = cld(hc + (size_t)(k - EE) * NB + lane);
    const float* wp = lw + k * 12;
    f4 w0 = *(const f4*)wp; f4 w1 = *(const f4*)(wp + 4); f4 w2 = *(const f4*)(wp + 8);
    ar += hv * w0; az += hv * w1; ah += hv * w2;
  }
  gru_combine_epi(smem, ar, az, ax, ah, jjb, HEN, bih, bhh, hc, ho, tt, lenp, nullptr);
}

// Decoder step: weights from global (cached, L2-resident), x = emb[tok].
// Coherent h-loads batched x4 (register-pressure bound by weight loads).
__device__ __forceinline__ void gru_dec(
    const P& p, char* smem, int jjb,
    const float* __restrict__ hc, float* ho)
{
  const int tid = threadIdx.x, lane = tid & 63, wv = tid >> 6;
  const float* wih = p.dwih; const float* whh = p.dwhh;
  const int KT = EE + HD;
  const int vs = (wv * KT) >> 3, ve = ((wv + 1) * KT) >> 3;
  f4 ar = {0,0,0,0}, az = {0,0,0,0}, ax = {0,0,0,0}, ah = {0,0,0,0};
  const int xe = ve < EE ? ve : EE;
  if (vs < EE) {
    const float* xr = p.emb + (size_t)cld(p.tok + lane) * EE;
    int k = vs;
    for (; k + 4 <= xe; k += 4) {
      float xv[4];
      #pragma unroll
      for (int u = 0; u < 4; u++) xv[u] = xr[k + u];
      #pragma unroll
      for (int u = 0; u < 4; u++) {
        #pragma unroll
        for (int j = 0; j < 4; j++) {
          int jj = jjb + j;
          ar[j] = fmaf(xv[u], wih[(size_t)jj * EE + k + u], ar[j]);
          az[j] = fmaf(xv[u], wih[(size_t)(HD + jj) * EE + k + u], az[j]);
          ax[j] = fmaf(xv[u], wih[(size_t)(2 * HD + jj) * EE + k + u], ax[j]);
        }
      }
    }
    for (; k < xe; k++) {
      float xv = xr[k];
      #pragma unroll
      for (int j = 0; j < 4; j++) {
        int jj = jjb + j;
        ar[j] = fmaf(xv, wih[(size_t)jj * EE + k], ar[j]);
        az[j] = fmaf(xv, wih[(size_t)(HD + jj) * EE + k], az[j]);
        ax[j] = fmaf(xv, wih[(size_t)(2 * HD + jj) * EE + k], ax[j]);
      }
    }
  }
  int hs = vs - EE; if (hs < 0) hs = 0;
  const int he = ve - EE;
  int k = hs;
  for (; k + 4 <= he; k += 4) {
    float hv[4];
    #pragma unroll
    for (int u = 0; u < 4; u++) hv[u] = cld(hc + (size_t)(k + u) * NB + lane);
    #pragma unroll
    for (int u = 0; u < 4; u++) {
      #pragma unroll
      for (int j = 0; j < 4; j++) {
        int jj = jjb + j;
        ar[j] = fmaf(hv[u], whh[(size_t)jj * HD + k + u], ar[j]);
        az[j] = fmaf(hv[u], whh[(size_t)(HD + jj) * HD + k + u], az[j]);
        ah[j] = fmaf(hv[u], whh[(size_t)(2 * HD + jj) * HD + k + u], ah[j]);
      }
    }
  }
  for (; k < he; k++) {
    float hv = cld(hc + (size_t)k * NB + lane);
    #pragma unroll
    for (int j = 0; j < 4; j++) {
      int jj = jjb + j;
      ar[j] = fmaf(hv, whh[(size_t)jj * HD + k], ar[j]);
      az[j] = fmaf(hv, whh[(size_t)(HD + jj) * HD + k], az[j]);
      ah[j] = fmaf(hv, whh[(size_t)(2 * HD + jj) * HD + k], ah[j]);
    }
  }
  gru_combine_epi(smem, ar, az, ax, ah, jjb, HD, p.dbih, p.dbhh,
                  hc, ho, -1, nullptr, p.hbf);
}

// ================= kernel 1: one-time prep (plain dispatch) =================
__global__ void __launch_bounds__(TPB, 2) prep_kernel(P p) {
  const int wg = blockIdx.x, tid = threadIdx.x;
  const int lane = tid & 63, wv = tid >> 6;
  const int gtid = wg * TPB + tid;
  // out_w -> bf16 copy + per-row L2 norm (certified rescue bound)
  int gwv = wg * 8 + wv;
  for (int v = gwv; v < VV; v += 2048) {
    const float* wr = p.outw + (size_t)v * HD + lane * 16;
    u16* dst = p.owbf + (size_t)v * HD + lane * 16;
    float sa = 0.f;
    u32 pk[8];
    #pragma unroll
    for (int q = 0; q < 4; q++) {
      float4 f = *(const float4*)(wr + q * 4);
      sa += f.x * f.x + f.y * f.y + f.z * f.z + f.w * f.w;
      pk[q * 2 + 0] = (u32)f2bf(f.x) | ((u32)f2bf(f.y) << 16);
      pk[q * 2 + 1] = (u32)f2bf(f.z) | ((u32)f2bf(f.w) << 16);
    }
    *(uint4*)(dst)     = make_uint4(pk[0], pk[1], pk[2], pk[3]);
    *(uint4*)(dst + 8) = make_uint4(pk[4], pk[5], pk[6], pk[7]);
    #pragma unroll
    for (int d = 1; d < 64; d <<= 1) sa += __shfl_xor(sa, d);
    if (lane == 0) p.wn[v] = sqrtf(sa);
  }
  // gather+transpose encoder inputs: xT[t][k][b] = emb[texts[b][t]][k]
  const long long tot = (long long)TT * NB * EE;
  for (long long i = gtid; i < tot; i += (long long)NWG * TPB) {
    int t = (int)(i / (NB * EE));
    int rr = (int)(i % (NB * EE));
    int b2 = rr / EE, k = rr % EE;
    float v = p.emb[(size_t)p.texts[b2 * TT + t] * EE + k];
    p.xT[((size_t)t * EE + k) * NB + b2] = v;
  }
}

// ================= kernel 2: bidirectional encoder (cooperative) ============
__global__ void __launch_bounds__(TPB, 1) enc_kernel(P p) {
  extern __shared__ __align__(16) char smem[];
  const int wg = blockIdx.x, tid = threadIdx.x;
  const int lane = tid & 63, wv = tid >> 6;
  const int gtid = wg * TPB + tid;
  u32 ebD = 0, ebF = 0;
  const int dir = wg >> 7;           // wgs 0..127 fwd, 128..255 bwd
  const int ejjb = (wg & 127) * 4;

  // stage this wg's encoder weight slice into LDS: lw[k][g*4+j]
  {
    const float* wih = dir ? p.ewih1 : p.ewih0;
    const float* whh = dir ? p.ewhh1 : p.ewhh0;
    float* lw = (float*)smem;
    for (int c = wv; c < 12; c += 8) {
      int g = c >> 2, j = c & 3;
      const float* sx = wih + (size_t)(g * HEN + ejjb + j) * EE;
      for (int k = lane; k < EE; k += 64) lw[k * 12 + c] = sx[k];
      const float* sh = whh + (size_t)(g * HEN + ejjb + j) * HEN;
      for (int k = lane; k < HEN; k += 64) lw[(EE + k) * 12 + c] = sh[k];
    }
  }
  __syncthreads();

  {
    const float* bih = dir ? p.ebih1 : p.ebih0;
    const float* bhh = dir ? p.ebhh1 : p.ebhh0;
    float* hbase = dir ? p.hTb : p.hTf;
    for (int t = 0; t < TT; t++) {
      int te = dir ? (TT - 1 - t) : t;
      const float* hc = hbase + (size_t)(t & 1) * HEN * NB;
      float* ho = hbase + (size_t)((t + 1) & 1) * HEN * NB;
      gru_enc(smem, ejjb, p.xT + (size_t)te * EE * NB, bih, bhh, hc, ho, te, p.len);
      gbarx(p.bar + BD_GRP + ((wg >> 4) << 6),
            p.bar + BD_ROOT + dir * 64, p.bar + BD_EPO + dir * 64, ebD++, 16u, 8u);
    }
  }
  // join fwd+bwd, then concat + tok init
  gbarx(p.bar + BF_GRP + ((wg >> 4) << 6),
        p.bar + BF_ROOT, p.bar + BF_EPO, ebF++, 16u, 16u);
  for (int i = gtid; i < HD * NB; i += NWG * TPB) {
    int k = i / NB, b2 = i % NB;
    float v = (k < HEN) ? cld(p.hTf + (size_t)k * NB + b2)
                        : cld(p.hTb + (size_t)(k - HEN) * NB + b2);
    cst(p.hTd + i, v);
  }
  if (gtid < NB) cst(p.tok + gtid, 1);   // sos
}

// ================= kernel 3: decoder (cooperative) ==========================
__global__ void __launch_bounds__(TPB, 1) dec_kernel(P p) {
  extern __shared__ __align__(16) char smem[];
  const int wg = blockIdx.x, tid = threadIdx.x;
  const int lane = tid & 63, wv = tid >> 6;
  u32 ebX = 0;

  for (int s = 0; s < DEC; s++) {
    const float* hc = p.hTd + (size_t)(s & 1) * HD * NB;
    float* ho = p.hTd + (size_t)((s + 1) & 1) * HD * NB;
    // 3a: GRU step (emits bf16 row-major h)
    gru_dec(p, smem, wg * 4, hc, ho);
    gbarx(p.bar + BX_GRP + ((wg >> 4) << 6),
          p.bar + BX_ROOT, p.bar + BX_EPO, ebX++, 16u, 16u);
    // 3b: bf16 MFMA logits + per-tile certified (lo,up) interval keys.
    {
      u16* hA = (u16*)smem;                 // [64][128 chunks of 16B], swizzled
      float* hsq = (float*)(smem + PBOFF);  // [64]
      const int l15 = lane & 15, quad = lane >> 4;
      const int gw = wg * 8 + wv;
      const bool two = (gw + 2048) < NTL;
      if (tid < 64) hsq[tid] = 0.f;
      __syncthreads();
      const u64* hb64 = (const u64*)p.hbf;        // 16384 u64, linear
      u64* hA64 = (u64*)hA;
      #pragma unroll 1
      for (int ii = 0; ii < 32; ii += 4) {        // stage full hbf + ||h||^2
        u64 q[4];
        #pragma unroll
        for (int u = 0; u < 4; u++)
          q[u] = cld(hb64 + (size_t)(tid + (ii + u) * TPB));
        #pragma unroll
        for (int u = 0; u < 4; u++) {
          int i = tid + (ii + u) * TPB;
          int r = i >> 8, c = i & 255;
          int cc = c >> 1;                        // 16B chunk index
          hA64[(size_t)r * 256 + ((cc ^ (r & 7)) * 2) + (c & 1)] = q[u];
          u32 uu[2] = {(u32)q[u], (u32)(q[u] >> 32)};
          float sq = 0.f;
          #pragma unroll
          for (int t2 = 0; t2 < 2; t2++) {
            float lo = __uint_as_float(uu[t2] << 16);
            float hi = __uint_as_float(uu[t2] & 0xffff0000u);
            sq = fmaf(lo, lo, fmaf(hi, hi, sq));
          }
          atomicAdd(&hsq[r], sq);
        }
      }
      __syncthreads();
      f4 acc0[4], acc1[4];
      #pragma unroll
      for (int m = 0; m < 4; m++) {
        #pragma unroll
        for (int r = 0; r < 4; r++) { acc0[m][r] = 0.f; acc1[m][r] = 0.f; }
      }
      const u16* bp0 = p.owbf + (size_t)(gw * 16 + l15) * HD + quad * 8;  // cached
      const u16* bp1 = bp0 + (size_t)2048 * 16 * HD;
      const int x7 = l15 & 7;
      const u16* hrow = hA + l15 * 1024;
      #pragma unroll 4
      for (int kc = 0; kc < 32; kc++) {
        int ci = ((kc * 4 + quad) ^ x7) * 8;
        s8 b0 = *(const s8*)(bp0 + kc * 32);
        s8 a0 = *(const s8*)(hrow + ci);
        s8 a1 = *(const s8*)(hrow + 16384 + ci);
        s8 a2 = *(const s8*)(hrow + 32768 + ci);
        s8 a3 = *(const s8*)(hrow + 49152 + ci);
        acc0[0] = __builtin_amdgcn_mfma_f32_16x16x32_bf16(a0, b0, acc0[0], 0, 0, 0);
        acc0[1] = __builtin_amdgcn_mfma_f32_16x16x32_bf16(a1, b0, acc0[1], 0, 0, 0);
        acc0[2] = __builtin_amdgcn_mfma_f32_16x16x32_bf16(a2, b0, acc0[2], 0, 0, 0);
        acc0[3] = __builtin_amdgcn_mfma_f32_16x16x32_bf16(a3, b0, acc0[3], 0, 0, 0);
        if (two) {
          s8 b1 = *(const s8*)(bp1 + kc * 32);
          acc1[0] = __builtin_amdgcn_mfma_f32_16x16x32_bf16(a0, b1, acc1[0], 0, 0, 0);
          acc1[1] = __builtin_amdgcn_mfma_f32_16x16x32_bf16(a1, b1, acc1[1], 0, 0, 0);
          acc1[2] = __builtin_amdgcn_mfma_f32_16x16x32_bf16(a2, b1, acc1[2], 0, 0, 0);
          acc1[3] = __builtin_amdgcn_mfma_f32_16x16x32_bf16(a3, b1, acc1[3], 0, 0, 0);
        }
      }
      float hroot[4][4];
      #pragma unroll
      for (int m = 0; m < 4; m++)
        #pragma unroll
        for (int r = 0; r < 4; r++)
          hroot[m][r] = sqrtf(hsq[m * 16 + quad * 4 + r]);
      auto epi = [&](int nt, f4* acc) {
        int col = nt * 16 + l15;
        float bias = p.outb[col];
        float wnc = p.wn[col];
        #pragma unroll
        for (int m = 0; m < 4; m++) {
          #pragma unroll
          for (int r = 0; r < 4; r++) {
            float v = acc[m][r] + bias;
            float e = RESC * hroot[m][r] * wnc + 1e-5f;
            u32 klo = fkey(v - e), kup = fkey(v + e);
            #pragma unroll
            for (int d = 1; d < 16; d <<= 1) {
              u32 ol = __shfl_xor(klo, d); if (ol > klo) klo = ol;
              u32 ou = __shfl_xor(kup, d); if (ou > kup) kup = ou;
            }
            if (l15 == 0)   // batch-major: prt[row][nt], dense per-batch scans
              cst(p.prt + (size_t)(m * 16 + quad * 4 + r) * NTLP + nt,
                  ((u64)klo << 32) | kup);
          }
        }
      };
      epi(gw, acc0);
      if (two) epi(gw + 2048, acc1);
    }
    gbarx(p.bar + BX_GRP + ((wg >> 4) << 6),
          p.bar + BX_ROOT, p.bar + BX_EPO, ebX++, 16u, 16u);
    // 3c: threshold T = max lo; rescue every tile with up >= T in exact fp32
    if (wg < NB) {
      const int b = wg;
      char* ms = smem + PBOFF;
      float* hb = (float*)ms;                   // [1024] exact fp32 h
      u64* red = (u64*)(ms + 4096);             // [8]
      u64* gmp = (u64*)(ms + 4160);
      u64* bestp = (u64*)(ms + 4168);
      int* ncp = (int*)(ms + 4176);
      int* list = (int*)(ms + 4192);            // [LCAP]
      for (int i = tid; i < HD; i += TPB) hb[i] = cld(ho + (size_t)i * NB + b);
      if (tid == 0) { *bestp = 0ull; *ncp = 0; }
      __syncthreads();
      // pass 1: dense coalesced scan of this batch's prt row, values cached in regs
      u64 pv[7];
      u64 mx = 0;
      #pragma unroll
      for (int i = 0; i < 7; i++) {
        int nt = tid + i * TPB;
        pv[i] = (nt < NTL) ? cld(p.prt + (size_t)b * NTLP + nt) : 0ull;
        if (pv[i] > mx) mx = pv[i];
      }
      #pragma unroll
      for (int d = 1; d < 64; d <<= 1) { u64 o = __shfl_xor(mx, d); if (o > mx) mx = o; }
      if (lane == 0) red[wv] = mx;
      __syncthreads();
      if (tid == 0) {
        u64 g = red[0];
        for (int w2 = 1; w2 < 8; w2++) if (red[w2] > g) g = red[w2];
        *gmp = g;
      }
      __syncthreads();
      const u32 thr = (u32)(*gmp >> 32);        // fkey(T), T = max of lo
      // pass 2: filter from registers (no memory)
      #pragma unroll
      for (int i = 0; i < 7; i++) {
        if ((u32)pv[i] >= thr) {                // up >= T (nt<NTL implied: pv=0 else)
          int ix = atomicAdd(ncp, 1);
          if (ix < LCAP) list[ix] = tid + i * TPB;
        }
      }
      __syncthreads();
      int total = *ncp;
      int nc = total < LCAP ? total : LCAP;
      const int c16 = tid >> 5, seg = tid & 31;
      u64 lb = 0;
      auto rescue = [&](int nt) {
        int v = nt * 16 + c16;
        const float* wr = p.outw + (size_t)v * HD;   // read-only, cached
        float sm = 0.f;
        #pragma unroll 8
        for (int i = 0; i < 32; i++) {
          int k = seg + 32 * i;
          sm = fmaf(hb[k], wr[k], sm);
        }
        #pragma unroll
        for (int d = 1; d < 32; d <<= 1) sm += __shfl_xor(sm, d);
        if (seg == 0) {
          float lg = sm + p.outb[v];
          u64 k2 = ((u64)fkey(lg) << 32) | (~(u32)v);   // ~v: lowest idx wins ties
          if (k2 > lb) lb = k2;
        }
      };
      for (int ci = 0; ci < nc; ci++) rescue(list[ci]);
      if (total > LCAP) {                       // certified fallback
        for (int nt = 0; nt < NTL; nt++)
          if ((u32)cld(p.prt + (size_t)b * NTLP + nt) >= thr) rescue(nt);
      }
      if (seg == 0 && lb) atomicMax((unsigned long long*)bestp, lb);
      __syncthreads();
      if (tid == 0) {
        u32 v = ~(u32)(*bestp);
        cst(p.tok + b, (int)v);
        p.out[b * DEC + s] = (float)v;
      }
    }
    gbarx(p.bar + BX_GRP + ((wg >> 4) << 6),
          p.bar + BX_ROOT, p.bar + BX_EPO, ebX++, 16u, 16u);
  }
}

__global__ void seq2seq_init(u32* bar, float* hTf, float* hTb) {
  int g = blockIdx.x * blockDim.x + threadIdx.x;
  if (g < BAR_WORDS) bar[g] = 0u;
  int n = 2 * HEN * NB;
  for (int i = g; i < n; i += gridDim.x * blockDim.x) { hTf[i] = 0.f; hTb[i] = 0.f; }
}

extern "C" void kernel_launch(void* const* d_in, const int* in_sizes, int n_in,
                              void* d_out, int out_size, void* d_ws, size_t ws_size,
                              hipStream_t stream) {
  char* w = (char*)d_ws;
  size_t off = 0;
  auto carve = [&](size_t n) {
    void* q = w + off;
    off = (off + n + 255) & ~(size_t)255;
    return q;
  };
  P p;
  p.texts = (const int*)d_in[0];
  p.len   = (const int*)d_in[1];
  p.emb   = (const float*)d_in[2];
  p.ewih0 = (const float*)d_in[3];  p.ewhh0 = (const float*)d_in[4];
  p.ebih0 = (const float*)d_in[5];  p.ebhh0 = (const float*)d_in[6];
  p.ewih1 = (const float*)d_in[7];  p.ewhh1 = (const float*)d_in[8];
  p.ebih1 = (const float*)d_in[9];  p.ebhh1 = (const float*)d_in[10];
  p.dwih  = (const float*)d_in[11]; p.dwhh  = (const float*)d_in[12];
  p.dbih  = (const float*)d_in[13]; p.dbhh  = (const float*)d_in[14];
  p.outw  = (const float*)d_in[15]; p.outb  = (const float*)d_in[16];
  p.out   = (float*)d_out;
  p.owbf  = (u16*)carve((size_t)VV * HD * 2);
  p.xT    = (float*)carve((size_t)TT * EE * NB * 4);
  p.hTf   = (float*)carve((size_t)2 * HEN * NB * 4);
  p.hTb   = (float*)carve((size_t)2 * HEN * NB * 4);
  p.hTd   = (float*)carve((size_t)2 * HD * NB * 4);
  p.hbf   = (u16*)carve((size_t)NB * HD * 2);
  p.prt   = (u64*)carve((size_t)NB * NTLP * 8);
  p.tok   = (int*)carve(256);
  p.wn    = (float*)carve((size_t)VV * 4);
  p.bar   = (u32*)carve(BAR_WORDS * 4);
  if (off > ws_size) return;  // workspace too small: fail visibly

  hipFuncSetAttribute((const void*)enc_kernel,
                      hipFuncAttributeMaxDynamicSharedMemorySize, SMEMSZ);
  hipFuncSetAttribute((const void*)dec_kernel,
                      hipFuncAttributeMaxDynamicSharedMemorySize, SMEMSZ);

  hipLaunchKernelGGL(seq2seq_init, dim3(64), dim3(256), 0, stream,
                     p.bar, p.hTf, p.hTb);
  hipLaunchKernelGGL(prep_kernel, dim3(NWG), dim3(TPB), 0, stream, p);
  void* args[] = { &p };
  hipError_t e = hipLaunchCooperativeKernel((void*)enc_kernel,
                                            dim3(NWG), dim3(TPB), args, SMEMSZ, stream);
  if (e != hipSuccess) {
    enc_kernel<<<dim3(NWG), dim3(TPB), SMEMSZ, stream>>>(p);
  }
  e = hipLaunchCooperativeKernel((void*)dec_kernel,
                                 dim3(NWG), dim3(TPB), args, SMEMSZ, stream);
  if (e != hipSuccess) {
    dec_kernel<<<dim3(NWG), dim3(TPB), SMEMSZ, stream>>>(p);
  }
}

// Round 6
// 14696.829 us; speedup vs baseline: 1.6775x; 1.2236x over previous
//
#include <hip/hip_runtime.h>
#include <stdint.h>

typedef unsigned int u32;
typedef unsigned long long u64;
typedef unsigned short u16;
typedef __attribute__((ext_vector_type(8))) short s8;
typedef __attribute__((ext_vector_type(4))) float f4;

#define NWG 256
#define TPB 512
#define NB 64      // batch
#define TT 400     // seq len
#define EE 300     // embed dim
#define HEN 512    // encoder hidden
#define HD 1024    // decoder hidden
#define VV 50000   // vocab
#define DEC 80     // decode steps
#define NTL 3125   // VV/16 n-tiles
#define NTLP 3136  // padded row stride for batch-major prt
#define LCAP 512   // rescue list capacity
#define EOFF 39168             // enc LDS: [0,EOFF) weights, [EOFF,+16K) combine
#define LGOFF 131072           // dec_logits LDS: [0,128K) hA, +256 hsq
#define LGSZ (LGOFF + 256)
#define RESC 0.00837f          // 2^-8 * 1.002 * 2.09 safety (bf16 h + bf16 w + fp32 acc)

// All cross-workgroup communication is INTER-DISPATCH: each phase is its own
// kernel; dispatch boundaries on the stream provide release/acquire (L2
// writeback+invalidate by the CP), so plain cached loads/stores are safe and
// mutable data stays L2-resident within a dispatch. No cooperative launch,
// no device barriers, no cache-bypassing atomics.

struct P {
  const int* texts; const int* len; const float* emb;
  const float* ewih0; const float* ewhh0; const float* ebih0; const float* ebhh0;
  const float* ewih1; const float* ewhh1; const float* ebih1; const float* ebhh1;
  const float* dwih; const float* dwhh; const float* dbih; const float* dbhh;
  const float* outw; const float* outb;
  float* out;
  u16* owbf; float* xT; float* hTf; float* hTb; float* hTd; u16* hbf;
  u64* prt; int* tok; float* wn;
};

__device__ __forceinline__ u32 fkey(float v) {
  u32 u = __float_as_uint(v);
  return (u & 0x80000000u) ? ~u : (u | 0x80000000u);
}
__device__ __forceinline__ u16 f2bf(float f) {   // RNE fp32->bf16
  u32 u = __float_as_uint(f);
  u32 r = u + 0x7FFFu + ((u >> 16) & 1u);
  return (u16)(r >> 16);
}
__device__ __forceinline__ float sigm(float x) { return 1.f / (1.f + expf(-x)); }

// ---- shared GRU epilogue: two-stage partial combine in 16KB LDS + activations
__device__ __forceinline__ void gru_combine_epi(
    float* pb, const f4& ar, const f4& az, const f4& ax, const f4& ah,
    int jjb, int HL, const float* bih, const float* bhh,
    const float* hc, float* ho, int mask_t, const int* lenp, u16* hbf_out)
{
  const int tid = threadIdx.x, lane = tid & 63, wv = tid >> 6;
  const int wl = wv & 3;
  if (wv < 4) {
    #pragma unroll
    for (int j = 0; j < 4; j++) {
      pb[((wl * 16 + j * 4 + 0) * 64) + lane] = ar[j];
      pb[((wl * 16 + j * 4 + 1) * 64) + lane] = az[j];
      pb[((wl * 16 + j * 4 + 2) * 64) + lane] = ax[j];
      pb[((wl * 16 + j * 4 + 3) * 64) + lane] = ah[j];
    }
  }
  __syncthreads();
  if (wv >= 4) {
    #pragma unroll
    for (int j = 0; j < 4; j++) {
      pb[((wl * 16 + j * 4 + 0) * 64) + lane] += ar[j];
      pb[((wl * 16 + j * 4 + 1) * 64) + lane] += az[j];
      pb[((wl * 16 + j * 4 + 2) * 64) + lane] += ax[j];
      pb[((wl * 16 + j * 4 + 3) * 64) + lane] += ah[j];
    }
  }
  __syncthreads();
  if (tid < 256) {
    int b = tid & 63, j = tid >> 6;
    int jj = jjb + j;
    float r = 0, z = 0, xn = 0, hn = 0;
    #pragma unroll
    for (int w = 0; w < 4; w++) {
      int base = ((w * 16 + j * 4) * 64) + b;
      r  += pb[base];
      z  += pb[base + 64];
      xn += pb[base + 128];
      hn += pb[base + 192];
    }
    r = sigm(r + bih[jj] + bhh[jj]);
    z = sigm(z + bih[HL + jj] + bhh[HL + jj]);
    float nn = tanhf(xn + bih[2 * HL + jj] + r * (hn + bhh[2 * HL + jj]));
    float hold = hc[(size_t)jj * NB + b];
    float hv = (1.f - z) * nn + z * hold;
    if (lenp && mask_t >= lenp[b]) hv = hold;
    ho[(size_t)jj * NB + b] = hv;
    if (hbf_out) hbf_out[(size_t)b * HD + jj] = f2bf(hv);
  }
}

// ================= prep: one-time (plain dispatch) =================
__global__ void __launch_bounds__(TPB, 2) prep_kernel(P p) {
  const int wg = blockIdx.x, tid = threadIdx.x;
  const int lane = tid & 63, wv = tid >> 6;
  const int gtid = wg * TPB + tid;
  int gwv = wg * 8 + wv;
  for (int v = gwv; v < VV; v += 2048) {
    const float* wr = p.outw + (size_t)v * HD + lane * 16;
    u16* dst = p.owbf + (size_t)v * HD + lane * 16;
    float sa = 0.f;
    u32 pk[8];
    #pragma unroll
    for (int q = 0; q < 4; q++) {
      float4 f = *(const float4*)(wr + q * 4);
      sa += f.x * f.x + f.y * f.y + f.z * f.z + f.w * f.w;
      pk[q * 2 + 0] = (u32)f2bf(f.x) | ((u32)f2bf(f.y) << 16);
      pk[q * 2 + 1] = (u32)f2bf(f.z) | ((u32)f2bf(f.w) << 16);
    }
    *(uint4*)(dst)     = make_uint4(pk[0], pk[1], pk[2], pk[3]);
    *(uint4*)(dst + 8) = make_uint4(pk[4], pk[5], pk[6], pk[7]);
    #pragma unroll
    for (int d = 1; d < 64; d <<= 1) sa += __shfl_xor(sa, d);
    if (lane == 0) p.wn[v] = sqrtf(sa);
  }
  const long long tot = (long long)TT * NB * EE;
  for (long long i = gtid; i < tot; i += (long long)NWG * TPB) {
    int t = (int)(i / (NB * EE));
    int rr = (int)(i % (NB * EE));
    int b2 = rr / EE, k = rr % EE;
    float v = p.emb[(size_t)p.texts[b2 * TT + t] * EE + k];
    p.xT[((size_t)t * EE + k) * NB + b2] = v;
  }
}

// ================= encoder: one dispatch per timestep ======================
__global__ void __launch_bounds__(TPB, 1) enc_step_kernel(P p, int t) {
  __shared__ __align__(16) char smem[EOFF + 16384];
  const int wg = blockIdx.x, tid = threadIdx.x;
  const int lane = tid & 63, wv = tid >> 6;
  const int dir = wg >> 7;           // wgs 0..127 fwd, 128..255 bwd
  const int ejjb = (wg & 127) * 4;

  // stage this wg's weight slice (re-staged each step; slice stays L2-warm)
  {
    const float* wih = dir ? p.ewih1 : p.ewih0;
    const float* whh = dir ? p.ewhh1 : p.ewhh0;
    float* lw = (float*)smem;
    for (int c = wv; c < 12; c += 8) {
      int g = c >> 2, j = c & 3;
      const float* sx = wih + (size_t)(g * HEN + ejjb + j) * EE;
      for (int k = lane; k < EE; k += 64) lw[k * 12 + c] = sx[k];
      const float* sh = whh + (size_t)(g * HEN + ejjb + j) * HEN;
      for (int k = lane; k < HEN; k += 64) lw[(EE + k) * 12 + c] = sh[k];
    }
  }
  __syncthreads();

  const float* bih = dir ? p.ebih1 : p.ebih0;
  const float* bhh = dir ? p.ebhh1 : p.ebhh0;
  float* hbase = dir ? p.hTb : p.hTf;
  const int te = dir ? (TT - 1 - t) : t;
  const float* hc = hbase + (size_t)(t & 1) * HEN * NB;
  float* ho = hbase + (size_t)((t + 1) & 1) * HEN * NB;
  const float* xsrc = p.xT + (size_t)te * EE * NB;

  const float* lw = (const float*)smem;
  const int KT = EE + HEN;
  const int vs = (wv * KT) >> 3, ve = ((wv + 1) * KT) >> 3;
  f4 ar = {0,0,0,0}, az = {0,0,0,0}, ax = {0,0,0,0}, ah = {0,0,0,0};
  const int xe = ve < EE ? ve : EE;
  int k = vs;
  for (; k + 8 <= xe; k += 8) {
    float xv[8];
    #pragma unroll
    for (int u = 0; u < 8; u++) xv[u] = xsrc[(size_t)(k + u) * NB + lane];
    #pragma unroll
    for (int u = 0; u < 8; u++) {
      const float* wp = lw + (k + u) * 12;
      f4 w0 = *(const f4*)wp; f4 w1 = *(const f4*)(wp + 4); f4 w2 = *(const f4*)(wp + 8);
      ar += xv[u] * w0; az += xv[u] * w1; ax += xv[u] * w2;
    }
  }
  for (; k < xe; k++) {
    float xv = xsrc[(size_t)k * NB + lane];
    const float* wp = lw + k * 12;
    f4 w0 = *(const f4*)wp; f4 w1 = *(const f4*)(wp + 4); f4 w2 = *(const f4*)(wp + 8);
    ar += xv * w0; az += xv * w1; ax += xv * w2;
  }
  k = vs > EE ? vs : EE;
  for (; k + 8 <= ve; k += 8) {
    float hv[8];
    #pragma unroll
    for (int u = 0; u < 8; u++) hv[u] = hc[(size_t)(k + u - EE) * NB + lane];
    #pragma unroll
    for (int u = 0; u < 8; u++) {
      const float* wp = lw + (k + u) * 12;
      f4 w0 = *(const f4*)wp; f4 w1 = *(const f4*)(wp + 4); f4 w2 = *(const f4*)(wp + 8);
      ar += hv[u] * w0; az += hv[u] * w1; ah += hv[u] * w2;
    }
  }
  for (; k < ve; k++) {
    float hv = hc[(size_t)(k - EE) * NB + lane];
    const float* wp = lw + k * 12;
    f4 w0 = *(const f4*)wp; f4 w1 = *(const f4*)(wp + 4); f4 w2 = *(const f4*)(wp + 8);
    ar += hv * w0; az += hv * w1; ah += hv * w2;
  }
  gru_combine_epi((float*)(smem + EOFF), ar, az, ax, ah, ejjb, HEN,
                  bih, bhh, hc, ho, te, p.len, nullptr);
}

// ================= encoder join: concat + tok init =========================
__global__ void enc_join_kernel(P p) {
  int g = blockIdx.x * blockDim.x + threadIdx.x;
  int stride = gridDim.x * blockDim.x;
  for (int i = g; i < HD * NB; i += stride) {
    int k = i / NB, b2 = i % NB;
    float v = (k < HEN) ? p.hTf[(size_t)k * NB + b2]
                        : p.hTb[(size_t)(k - HEN) * NB + b2];
    p.hTd[i] = v;
  }
  if (g < NB) p.tok[g] = 1;   // sos
}

// ================= decoder 3a: GRU step (per-step dispatch) ================
__global__ void __launch_bounds__(TPB, 1) dec_gru_kernel(P p, int s) {
  __shared__ __align__(16) float pb[4096];
  const int wg = blockIdx.x, tid = threadIdx.x;
  const int lane = tid & 63, wv = tid >> 6;
  const int jjb = wg * 4;
  const float* hc = p.hTd + (size_t)(s & 1) * HD * NB;
  float* ho = p.hTd + (size_t)((s + 1) & 1) * HD * NB;
  const float* wih = p.dwih; const float* whh = p.dwhh;
  const int KT = EE + HD;
  const int vs = (wv * KT) >> 3, ve = ((wv + 1) * KT) >> 3;
  f4 ar = {0,0,0,0}, az = {0,0,0,0}, ax = {0,0,0,0}, ah = {0,0,0,0};
  const int xe = ve < EE ? ve : EE;
  if (vs < EE) {
    const float* xr = p.emb + (size_t)p.tok[lane] * EE;
    int k = vs;
    for (; k + 4 <= xe; k += 4) {
      float xv[4];
      #pragma unroll
      for (int u = 0; u < 4; u++) xv[u] = xr[k + u];
      #pragma unroll
      for (int u = 0; u < 4; u++) {
        #pragma unroll
        for (int j = 0; j < 4; j++) {
          int jj = jjb + j;
          ar[j] = fmaf(xv[u], wih[(size_t)jj * EE + k + u], ar[j]);
          az[j] = fmaf(xv[u], wih[(size_t)(HD + jj) * EE + k + u], az[j]);
          ax[j] = fmaf(xv[u], wih[(size_t)(2 * HD + jj) * EE + k + u], ax[j]);
        }
      }
    }
    for (; k < xe; k++) {
      float xv = xr[k];
      #pragma unroll
      for (int j = 0; j < 4; j++) {
        int jj = jjb + j;
        ar[j] = fmaf(xv, wih[(size_t)jj * EE + k], ar[j]);
        az[j] = fmaf(xv, wih[(size_t)(HD + jj) * EE + k], az[j]);
        ax[j] = fmaf(xv, wih[(size_t)(2 * HD + jj) * EE + k], ax[j]);
      }
    }
  }
  int hs = vs - EE; if (hs < 0) hs = 0;
  const int he = ve - EE;
  int k = hs;
  for (; k + 4 <= he; k += 4) {
    float hv[4];
    #pragma unroll
    for (int u = 0; u < 4; u++) hv[u] = hc[(size_t)(k + u) * NB + lane];
    #pragma unroll
    for (int u = 0; u < 4; u++) {
      #pragma unroll
      for (int j = 0; j < 4; j++) {
        int jj = jjb + j;
        ar[j] = fmaf(hv[u], whh[(size_t)jj * HD + k + u], ar[j]);
        az[j] = fmaf(hv[u], whh[(size_t)(HD + jj) * HD + k + u], az[j]);
        ah[j] = fmaf(hv[u], whh[(size_t)(2 * HD + jj) * HD + k + u], ah[j]);
      }
    }
  }
  for (; k < he; k++) {
    float hv = hc[(size_t)k * NB + lane];
    #pragma unroll
    for (int j = 0; j < 4; j++) {
      int jj = jjb + j;
      ar[j] = fmaf(hv, whh[(size_t)jj * HD + k], ar[j]);
      az[j] = fmaf(hv, whh[(size_t)(HD + jj) * HD + k], az[j]);
      ah[j] = fmaf(hv, whh[(size_t)(2 * HD + jj) * HD + k], ah[j]);
    }
  }
  gru_combine_epi(pb, ar, az, ax, ah, jjb, HD, p.dbih, p.dbhh,
                  hc, ho, -1, nullptr, p.hbf);
}

// ================= decoder 3b: logits MFMA + interval keys =================
__global__ void __launch_bounds__(TPB, 1) dec_logits_kernel(P p) {
  extern __shared__ __align__(16) char smem[];
  const int wg = blockIdx.x, tid = threadIdx.x;
  const int lane = tid & 63, wv = tid >> 6;
  u16* hA = (u16*)smem;                 // [64][128 chunks of 16B], swizzled
  float* hsq = (float*)(smem + LGOFF);  // [64]
  const int l15 = lane & 15, quad = lane >> 4;
  const int gw = wg * 8 + wv;
  const bool two = (gw + 2048) < NTL;
  if (tid < 64) hsq[tid] = 0.f;
  __syncthreads();
  for (int i = tid; i < 8192; i += TPB) {       // stage full hbf + ||h||^2
    int r = i >> 7, c = i & 127;
    uint4 q = *(const uint4*)(p.hbf + (size_t)r * HD + c * 8);
    *(uint4*)(hA + (size_t)r * 1024 + ((c ^ (r & 7)) * 8)) = q;
    u32 uu[4] = {q.x, q.y, q.z, q.w};
    float sq = 0.f;
    #pragma unroll
    for (int t2 = 0; t2 < 4; t2++) {
      float lo = __uint_as_float(uu[t2] << 16);
      float hi = __uint_as_float(uu[t2] & 0xffff0000u);
      sq = fmaf(lo, lo, fmaf(hi, hi, sq));
    }
    atomicAdd(&hsq[r], sq);
  }
  __syncthreads();
  f4 acc0[4], acc1[4];
  #pragma unroll
  for (int m = 0; m < 4; m++) {
    #pragma unroll
    for (int r = 0; r < 4; r++) { acc0[m][r] = 0.f; acc1[m][r] = 0.f; }
  }
  const u16* bp0 = p.owbf + (size_t)(gw * 16 + l15) * HD + quad * 8;
  const u16* bp1 = bp0 + (size_t)2048 * 16 * HD;
  const int x7 = l15 & 7;
  const u16* hrow = hA + l15 * 1024;
  #pragma unroll 4
  for (int kc = 0; kc < 32; kc++) {
    int ci = ((kc * 4 + quad) ^ x7) * 8;
    s8 b0 = *(const s8*)(bp0 + kc * 32);
    s8 a0 = *(const s8*)(hrow + ci);
    s8 a1 = *(const s8*)(hrow + 16384 + ci);
    s8 a2 = *(const s8*)(hrow + 32768 + ci);
    s8 a3 = *(const s8*)(hrow + 49152 + ci);
    acc0[0] = __builtin_amdgcn_mfma_f32_16x16x32_bf16(a0, b0, acc0[0], 0, 0, 0);
    acc0[1] = __builtin_amdgcn_mfma_f32_16x16x32_bf16(a1, b0, acc0[1], 0, 0, 0);
    acc0[2] = __builtin_amdgcn_mfma_f32_16x16x32_bf16(a2, b0, acc0[2], 0, 0, 0);
    acc0[3] = __builtin_amdgcn_mfma_f32_16x16x32_bf16(a3, b0, acc0[3], 0, 0, 0);
    if (two) {
      s8 b1 = *(const s8*)(bp1 + kc * 32);
      acc1[0] = __builtin_amdgcn_mfma_f32_16x16x32_bf16(a0, b1, acc1[0], 0, 0, 0);
      acc1[1] = __builtin_amdgcn_mfma_f32_16x16x32_bf16(a1, b1, acc1[1], 0, 0, 0);
      acc1[2] = __builtin_amdgcn_mfma_f32_16x16x32_bf16(a2, b1, acc1[2], 0, 0, 0);
      acc1[3] = __builtin_amdgcn_mfma_f32_16x16x32_bf16(a3, b1, acc1[3], 0, 0, 0);
    }
  }
  float hroot[4][4];
  #pragma unroll
  for (int m = 0; m < 4; m++)
    #pragma unroll
    for (int r = 0; r < 4; r++)
      hroot[m][r] = sqrtf(hsq[m * 16 + quad * 4 + r]);
  auto epi = [&](int nt, f4* acc) {
    int col = nt * 16 + l15;
    float bias = p.outb[col];
    float wnc = p.wn[col];
    #pragma unroll
    for (int m = 0; m < 4; m++) {
      #pragma unroll
      for (int r = 0; r < 4; r++) {
        float v = acc[m][r] + bias;
        float e = RESC * hroot[m][r] * wnc + 1e-5f;
        u32 klo = fkey(v - e), kup = fkey(v + e);
        #pragma unroll
        for (int d = 1; d < 16; d <<= 1) {
          u32 ol = __shfl_xor(klo, d); if (ol > klo) klo = ol;
          u32 ou = __shfl_xor(kup, d); if (ou > kup) kup = ou;
        }
        if (l15 == 0)   // batch-major: prt[row][nt], dense per-batch scans
          p.prt[(size_t)(m * 16 + quad * 4 + r) * NTLP + nt] =
              ((u64)klo << 32) | kup;
      }
    }
  };
  epi(gw, acc0);
  if (two) epi(gw + 2048, acc1);
}

// ================= decoder 3c: threshold + exact rescue (64 wgs) ===========
__global__ void __launch_bounds__(TPB, 1) dec_rescue_kernel(P p, int s) {
  __shared__ float hb[HD];
  __shared__ u64 red[8];
  __shared__ u64 gmp, bestp;
  __shared__ int ncp;
  __shared__ int list[LCAP];
  const int b = blockIdx.x, tid = threadIdx.x;
  const int lane = tid & 63, wv = tid >> 6;
  const float* ho = p.hTd + (size_t)((s + 1) & 1) * HD * NB;
  for (int i = tid; i < HD; i += TPB) hb[i] = ho[(size_t)i * NB + b];
  if (tid == 0) { bestp = 0ull; ncp = 0; }
  __syncthreads();
  // pass 1: dense coalesced scan of this batch's prt row, values kept in regs
  u64 pv[7];
  u64 mx = 0;
  #pragma unroll
  for (int i = 0; i < 7; i++) {
    int nt = tid + i * TPB;
    pv[i] = (nt < NTL) ? p.prt[(size_t)b * NTLP + nt] : 0ull;
    if (pv[i] > mx) mx = pv[i];
  }
  #pragma unroll
  for (int d = 1; d < 64; d <<= 1) { u64 o = __shfl_xor(mx, d); if (o > mx) mx = o; }
  if (lane == 0) red[wv] = mx;
  __syncthreads();
  if (tid == 0) {
    u64 g = red[0];
    for (int w2 = 1; w2 < 8; w2++) if (red[w2] > g) g = red[w2];
    gmp = g;
  }
  __syncthreads();
  const u32 thr = (u32)(gmp >> 32);        // fkey(T), T = max of lo
  // pass 2: filter from registers (no memory)
  #pragma unroll
  for (int i = 0; i < 7; i++) {
    if ((u32)pv[i] >= thr) {               // up >= T
      int ix = atomicAdd(&ncp, 1);
      if (ix < LCAP) list[ix] = tid + i * TPB;
    }
  }
  __syncthreads();
  int total = ncp;
  int nc = total < LCAP ? total : LCAP;
  const int c16 = tid >> 5, seg = tid & 31;
  u64 lb = 0;
  auto rescue = [&](int nt) {
    int v = nt * 16 + c16;
    const float* wr = p.outw + (size_t)v * HD;
    float sm = 0.f;
    #pragma unroll 8
    for (int i = 0; i < 32; i++) {
      int k = seg + 32 * i;
      sm = fmaf(hb[k], wr[k], sm);
    }
    #pragma unroll
    for (int d = 1; d < 32; d <<= 1) sm += __shfl_xor(sm, d);
    if (seg == 0) {
      float lg = sm + p.outb[v];
      u64 k2 = ((u64)fkey(lg) << 32) | (~(u32)v);   // ~v: lowest idx wins ties
      if (k2 > lb) lb = k2;
    }
  };
  for (int ci = 0; ci < nc; ci++) rescue(list[ci]);
  if (total > LCAP) {                      // certified fallback
    for (int nt = 0; nt < NTL; nt++)
      if ((u32)p.prt[(size_t)b * NTLP + nt] >= thr) rescue(nt);
  }
  if (seg == 0 && lb) atomicMax((unsigned long long*)&bestp, lb);
  __syncthreads();
  if (tid == 0) {
    u32 v = ~(u32)(bestp);
    p.tok[b] = (int)v;
    p.out[b * DEC + s] = (float)v;
  }
}

__global__ void seq2seq_init(float* hTf, float* hTb) {
  int g = blockIdx.x * blockDim.x + threadIdx.x;
  int n = 2 * HEN * NB;
  for (int i = g; i < n; i += gridDim.x * blockDim.x) { hTf[i] = 0.f; hTb[i] = 0.f; }
}

extern "C" void kernel_launch(void* const* d_in, const int* in_sizes, int n_in,
                              void* d_out, int out_size, void* d_ws, size_t ws_size,
                              hipStream_t stream) {
  char* w = (char*)d_ws;
  size_t off = 0;
  auto carve = [&](size_t n) {
    void* q = w + off;
    off = (off + n + 255) & ~(size_t)255;
    return q;
  };
  P p;
  p.texts = (const int*)d_in[0];
  p.len   = (const int*)d_in[1];
  p.emb   = (const float*)d_in[2];
  p.ewih0 = (const float*)d_in[3];  p.ewhh0 = (const float*)d_in[4];
  p.ebih0 = (const float*)d_in[5];  p.ebhh0 = (const float*)d_in[6];
  p.ewih1 = (const float*)d_in[7];  p.ewhh1 = (const float*)d_in[8];
  p.ebih1 = (const float*)d_in[9];  p.ebhh1 = (const float*)d_in[10];
  p.dwih  = (const float*)d_in[11]; p.dwhh  = (const float*)d_in[12];
  p.dbih  = (const float*)d_in[13]; p.dbhh  = (const float*)d_in[14];
  p.outw  = (const float*)d_in[15]; p.outb  = (const float*)d_in[16];
  p.out   = (float*)d_out;
  p.owbf  = (u16*)carve((size_t)VV * HD * 2);
  p.xT    = (float*)carve((size_t)TT * EE * NB * 4);
  p.hTf   = (float*)carve((size_t)2 * HEN * NB * 4);
  p.hTb   = (float*)carve((size_t)2 * HEN * NB * 4);
  p.hTd   = (float*)carve((size_t)2 * HD * NB * 4);
  p.hbf   = (u16*)carve((size_t)NB * HD * 2);
  p.prt   = (u64*)carve((size_t)NB * NTLP * 8);
  p.tok   = (int*)carve(256);
  p.wn    = (float*)carve((size_t)VV * 4);
  if (off > ws_size) return;  // workspace too small: fail visibly

  hipFuncSetAttribute((const void*)dec_logits_kernel,
                      hipFuncAttributeMaxDynamicSharedMemorySize, LGSZ);

  seq2seq_init<<<dim3(64), dim3(256), 0, stream>>>(p.hTf, p.hTb);
  prep_kernel<<<dim3(NWG), dim3(TPB), 0, stream>>>(p);
  for (int t = 0; t < TT; t++)
    enc_step_kernel<<<dim3(NWG), dim3(TPB), 0, stream>>>(p, t);
  enc_join_kernel<<<dim3(64), dim3(256), 0, stream>>>(p);
  for (int s = 0; s < DEC; s++) {
    dec_gru_kernel<<<dim3(NWG), dim3(TPB), 0, stream>>>(p, s);
    dec_logits_kernel<<<dim3(NWG), dim3(TPB), LGSZ, stream>>>(p);
    dec_rescue_kernel<<<dim3(NB), dim3(TPB), 0, stream>>>(p, s);
  }
}